// Round 9
// baseline (241.149 us; speedup 1.0000x reference)
//
#include <hip/hip_runtime.h>
#include <math.h>

#define NN 4096
#define EE 131072
#define IN_DIM 512
#define HID 256
#define OUT_DIM 64
#define ECAP 128

typedef __attribute__((ext_vector_type(8))) short bf8_t;
typedef __attribute__((ext_vector_type(4))) float f4_t;
typedef __attribute__((ext_vector_type(8))) unsigned short us8_t;
typedef __attribute__((ext_vector_type(4))) unsigned short us4_t;

#define GAS __attribute__((address_space(1)))
#define LAS __attribute__((address_space(3)))

// ---------------- bf16 helpers (RNE) ----------------
__device__ __forceinline__ unsigned short f2bf(float v){
  union { float f; unsigned u; } x; x.f = v;
  unsigned r = x.u + 0x7fffu + ((x.u >> 16) & 1u);
  return (unsigned short)(r >> 16);
}
__device__ __forceinline__ float bf2f(unsigned short h){
  union { float f; unsigned u; } x; x.u = ((unsigned)h) << 16;
  return x.f;
}

__device__ __forceinline__ float waveReduceSum(float v){
#pragma unroll
  for (int off = 32; off > 0; off >>= 1) v += __shfl_down(v, off);
  return v;
}

// ---------------- mega-prep: zero bits + split x_in + transpose-split all weights ----------------
__global__ __launch_bounds__(256) void k_prep(
    const float* __restrict__ x_in, const float* __restrict__ dW0,
    const float* __restrict__ dW1, const float* __restrict__ dW2,
    const float* __restrict__ dW3, const float* __restrict__ uW0,
    const float* __restrict__ uW1, const float* __restrict__ uW2,
    unsigned* __restrict__ bits,
    unsigned short* __restrict__ xinh, unsigned short* __restrict__ xinl,
    unsigned short* __restrict__ W0th, unsigned short* __restrict__ W0tl,
    unsigned short* __restrict__ W5th, unsigned short* __restrict__ W5tl,
    unsigned short* __restrict__ W2th, unsigned short* __restrict__ W2tl)
{
  int b = blockIdx.x;
  if (b < 128){                       // zero 2MB bit-adjacency
    int base = b * 4096 + threadIdx.x;
#pragma unroll
    for (int i = 0; i < 16; ++i) bits[base + i * 256] = 0;
    return;
  }
  b -= 128;
  if (b < 2048){                      // split x_in (4096x512 fp32 -> bf16 hi/lo)
    int i0 = b * 1024 + threadIdx.x;
#pragma unroll
    for (int i = 0; i < 4; ++i){
      int idx = i0 + i * 256;
      float v = x_in[idx];
      unsigned short h = f2bf(v);
      xinh[idx] = h; xinl[idx] = f2bf(v - bf2f(h));
    }
    return;
  }
  b -= 2048;
  const float* X; unsigned short *Th, *Tl; int R, C, tile;
  if (b < 128){ X = dW0; Th = W0th; Tl = W0tl; R = 512; C = 256; tile = b; }
  else if (b < 448){
    int t2 = b - 128; int z = t2 >> 6; int rem = t2 & 63;
    const float* ws[5] = {dW1, dW2, dW3, uW0, uW1};
    X = ws[z]; Th = W5th + (size_t)z * 65536; Tl = W5tl + (size_t)z * 65536;
    R = 256; C = 256; tile = rem;
  } else { X = uW2; Th = W2th; Tl = W2tl; R = 256; C = 64; tile = b - 448; }
  int tpr = C >> 5;
  int bx = (tile % tpr) * 32, by = (tile / tpr) * 32;
  __shared__ float t[32][33];
  int tx = threadIdx.x & 31, ty = threadIdx.x >> 5;
#pragma unroll
  for (int i = 0; i < 4; ++i)
    t[ty + i * 8][tx] = X[(size_t)(by + ty + i * 8) * C + bx + tx];
  __syncthreads();
#pragma unroll
  for (int i = 0; i < 4; ++i){
    float v = t[tx][ty + i * 8];
    unsigned short h = f2bf(v);
    size_t o = (size_t)(bx + ty + i * 8) * R + by + tx;
    Th[o] = h; Tl[o] = f2bf(v - bf2f(h));
  }
}

// ---------------- graph build: bitmask + ELL ----------------
__global__ void k_build_bits(const int* __restrict__ ei, unsigned* __restrict__ bits){
  int e = blockIdx.x * blockDim.x + threadIdx.x;
  if (e < EE){
    int r = ei[e], c = ei[EE + e];
    atomicOr(&bits[r * 128 + (c >> 5)], 1u << (c & 31));
  }
}

__global__ __launch_bounds__(128) void k_ell(const unsigned* __restrict__ bits,
                                             int* __restrict__ ell, int* __restrict__ cnt,
                                             float* __restrict__ dinv){
  int r = blockIdx.x, t = threadIdx.x;
  unsigned w = bits[r * 128 + t];
  int c = __popc(w);
  __shared__ int sc[128];
  sc[t] = c; __syncthreads();
  for (int off = 1; off < 128; off <<= 1){
    int a = sc[t], b = (t >= off) ? sc[t - off] : 0;
    __syncthreads(); sc[t] = a + b; __syncthreads();
  }
  int total = sc[127];
  int pos = sc[t] - c;
  int base = r * ECAP;
  while (w){
    int b = __ffs(w) - 1; w &= w - 1;
    if (pos < ECAP) ell[base + pos] = t * 32 + b;
    pos++;
  }
  if (t == 0){
    cnt[r] = (total < ECAP) ? total : ECAP;
    dinv[r] = 1.0f / sqrtf((float)total + 2.0f);
  }
}

// ---------------- fused SpMM (ELL, values==1) + GCN epilogue (+ optional score) ----------------
template<int NCOLS, int RELU, int SC>
__global__ __launch_bounds__(256) void k_spmm_ell(
    const int* __restrict__ ell, const int* __restrict__ cnt,
    const float* __restrict__ Zs, const float* __restrict__ dinv,
    const float* __restrict__ bias, float* __restrict__ out,
    const float* __restrict__ scw, float* __restrict__ score)
{
  int r = blockIdx.x;
  __shared__ int s_idx[ECAP];
  __shared__ int s_n;
  __shared__ float sh[4 * NCOLS];
  __shared__ float sd[4], sq[4];
  if (threadIdx.x == 0) s_n = cnt[r];
  for (int i = threadIdx.x; i < ECAP; i += 256) s_idx[i] = ell[r * ECAP + i];
  __syncthreads();
  int n = s_n; if (n > ECAP) n = ECAP;
  int wv = threadIdx.x >> 6, lane = threadIdx.x & 63;
  if (NCOLS == 256){
    f4_t acc = (f4_t){0.f, 0.f, 0.f, 0.f};
    for (int e = wv; e < n; e += 4){
      const f4_t* row = (const f4_t*)(Zs + (size_t)s_idx[e] * 256);
      acc += row[lane];
    }
    ((f4_t*)(sh + wv * 256))[lane] = acc;
  } else {
    float acc = 0.f;
    for (int e = wv; e < n; e += 4)
      acc += Zs[(size_t)s_idx[e] * 64 + lane];
    sh[wv * 64 + lane] = acc;
  }
  __syncthreads();
  int t = threadIdx.x;
  float o = 0.f;
  if (t < NCOLS){
    float y = sh[t] + sh[NCOLS + t] + sh[2 * NCOLS + t] + sh[3 * NCOLS + t];
    float z = Zs[(size_t)r * NCOLS + t];
    o = dinv[r] * (y + 2.0f * z) + bias[t];
    if (RELU) o = fmaxf(o, 0.f);
    out[(size_t)r * NCOLS + t] = o;
  }
  if (SC){
    float w = scw[t];
    float d = waveReduceSum(o * w);
    float q = waveReduceSum(w * w);
    if (!lane){ sd[wv] = d; sq[wv] = q; }
    __syncthreads();
    if (!t) score[r] = tanhf((sd[0] + sd[1] + sd[2] + sd[3]) / sqrtf(sq[0] + sq[1] + sq[2] + sq[3]));
  }
}

// ---------------- A1@Z factored through A0 (two-pass ELL gather, fp32 exact) ----------------
// Pass 1: G[k][:] = sum_{j in ell[k], inv[j]>=0} Zs[inv[j]][:] + (inv[k]>=0 ? Zs[inv[k]][:] : 0)
__global__ __launch_bounds__(256) void k_gG(
    const int* __restrict__ ell, const int* __restrict__ cnt, const int* __restrict__ inv,
    const float* __restrict__ Zs, float* __restrict__ G)
{
  int k = blockIdx.x;
  __shared__ int s_idx[ECAP];
  __shared__ int s_n;
  __shared__ float sh[4 * 256];
  if (!threadIdx.x) s_n = cnt[k];
  __syncthreads();
  int n = s_n;
  for (int i = threadIdx.x; i < n; i += 256)
    s_idx[i] = inv[ell[k * ECAP + i]];
  __syncthreads();
  int wv = threadIdx.x >> 6, lane = threadIdx.x & 63;
  f4_t acc = (f4_t){0.f, 0.f, 0.f, 0.f};
  for (int e = wv; e < n; e += 4){
    int s = s_idx[e];
    if (s >= 0) acc += ((const f4_t*)(Zs + (size_t)s * 256))[lane];
  }
  if (wv == 0){
    int sk = inv[k];
    if (sk >= 0) acc += ((const f4_t*)(Zs + (size_t)sk * 256))[lane];
  }
  ((f4_t*)(sh + wv * 256))[lane] = acc;
  __syncthreads();
  int t = threadIdx.x;
  G[(size_t)k * 256 + t] = sh[t] + sh[256 + t] + sh[512 + t] + sh[768 + t];
}

// Pass 2: Y[r] = sum_{k in ell[pr]} G[k] + G[pr]; subtract diag1*Zs[r]; GCN epilogue.
// diag1 = sum_{k in ell[pr]} bit(k,pr) + 2*bit(pr,pr) + 1   (= A1_full[r][r])
// UP=0: out x1 + score. UP=1: scatter res[pr]+out -> Oh/Ol at row pr (bf16 split).
template<int UP>
__global__ __launch_bounds__(256) void k_gY(
    const int* __restrict__ ell, const int* __restrict__ cnt, const int* __restrict__ perm,
    const unsigned* __restrict__ bits,
    const float* __restrict__ G, const float* __restrict__ Zs, const float* __restrict__ dinv,
    const float* __restrict__ bias,
    float* __restrict__ outF, unsigned short* __restrict__ Oh, unsigned short* __restrict__ Ol,
    const float* __restrict__ scw, float* __restrict__ score, const float* __restrict__ res)
{
  int r = blockIdx.x;
  int pr = perm[r];
  __shared__ int s_idx[ECAP];
  __shared__ int s_n;
  __shared__ float sh[4 * 256];
  __shared__ float sdg[4], sd[4], sq[4];
  if (!threadIdx.x) s_n = cnt[pr];
  for (int i = threadIdx.x; i < ECAP; i += 256) s_idx[i] = ell[pr * ECAP + i];
  __syncthreads();
  int n = s_n;
  int wv = threadIdx.x >> 6, lane = threadIdx.x & 63;
  // diag1 partial (bit tests over ell[pr])
  float dg = 0.f;
  for (int e = threadIdx.x; e < n; e += 256){
    int k = s_idx[e];
    dg += (float)((bits[k * 128 + (pr >> 5)] >> (pr & 31)) & 1u);
  }
  dg = waveReduceSum(dg);
  if (!lane) sdg[wv] = dg;
  // gather G rows
  f4_t acc = (f4_t){0.f, 0.f, 0.f, 0.f};
  for (int e = wv; e < n; e += 4)
    acc += ((const f4_t*)(G + (size_t)s_idx[e] * 256))[lane];
  if (wv == 0) acc += ((const f4_t*)(G + (size_t)pr * 256))[lane];
  ((f4_t*)(sh + wv * 256))[lane] = acc;
  __syncthreads();
  float diag1 = sdg[0] + sdg[1] + sdg[2] + sdg[3]
              + 2.0f * (float)((bits[pr * 128 + (pr >> 5)] >> (pr & 31)) & 1u) + 1.0f;
  int t = threadIdx.x;
  float y = sh[t] + sh[256 + t] + sh[512 + t] + sh[768 + t];
  float z = Zs[(size_t)r * 256 + t];
  float o = dinv[r] * (y - diag1 * z + 2.0f * z) + bias[t];
  o = fmaxf(o, 0.f);
  if (UP){
    float comb = res[(size_t)pr * 256 + t] + o;
    unsigned short h = f2bf(comb);
    size_t od = (size_t)pr * 256 + t;
    Oh[od] = h; Ol[od] = f2bf(comb - bf2f(h));
  } else {
    outF[(size_t)r * 256 + t] = o;
    float w = scw[t];
    float d = waveReduceSum(o * w);
    float q = waveReduceSum(w * w);
    if (!lane){ sd[wv] = d; sq[wv] = q; }
    __syncthreads();
    if (!t) score[r] = tanhf((sd[0] + sd[1] + sd[2] + sd[3]) / sqrtf(sq[0] + sq[1] + sq[2] + sq[3]));
  }
}

// ---------------- pool1: pool_x2 + build_Rb (2-bit packed) + xu1 fill ----------------
__global__ __launch_bounds__(256) void k_pool_build(
    const float* __restrict__ x0, const float* __restrict__ score,
    const int* __restrict__ perm1, const int* __restrict__ inv1,
    const int* __restrict__ ell, const int* __restrict__ cnt,
    unsigned short* __restrict__ xph, unsigned short* __restrict__ xpl,
    unsigned short* __restrict__ Rb2,
    unsigned short* __restrict__ xu1h, unsigned short* __restrict__ xu1l)
{
  int b = blockIdx.x;
  if (b < 2048){                           // gated pooled features
    int pr = perm1[b]; float s = score[pr];
    int c = threadIdx.x;
    float v = x0[(size_t)pr * 256 + c] * s;
    unsigned short h = f2bf(v);
    xph[(size_t)b * 256 + c] = h;
    xpl[(size_t)b * 256 + c] = f2bf(v - bf2f(h));
    return;
  }
  if (b < 6144){                           // Rb2[k]: 2-bit packed (A0+I)[k][perm1[s]]
    int k = b - 2048;
    __shared__ unsigned char row[2048];
    for (int i = threadIdx.x; i < 512; i += 256) ((int*)row)[i] = 0;
    __syncthreads();
    int n = cnt[k];
    for (int e = threadIdx.x; e < n; e += 256){
      int s = inv1[ell[k * ECAP + e]];
      if (s >= 0) row[s] = 1;
    }
    __syncthreads();
    if (threadIdx.x == 0){
      int sk = inv1[k];
      if (sk >= 0) row[sk] += 1;
    }
    __syncthreads();
    unsigned w = 0;
#pragma unroll
    for (int j = 0; j < 8; ++j) w |= ((unsigned)row[(threadIdx.x << 3) + j]) << (2 * j);
    Rb2[k * 256 + threadIdx.x] = (unsigned short)w;
    return;
  }
  int r = b - 6144;                        // xu1 fill: non-selected rows = x0
  if (inv1[r] < 0){
    int c = threadIdx.x;
    float v = x0[(size_t)r * 256 + c];
    unsigned short h = f2bf(v);
    xu1h[(size_t)r * 256 + c] = h;
    xu1l[(size_t)r * 256 + c] = f2bf(v - bf2f(h));
  }
}

// ---------------- pool2/3 prep: pooled-x + xu fill + L row-gather(+I) + transpose-gather(+I) ----------------
template<int SRCL, int OUTL>
__global__ __launch_bounds__(256) void k_pp(
    const float* __restrict__ x, const float* __restrict__ score,
    const int* __restrict__ perm, const int* __restrict__ inv, int n, int k,
    unsigned short* __restrict__ xph, unsigned short* __restrict__ xpl,
    unsigned short* __restrict__ xuh, unsigned short* __restrict__ xul,
    const unsigned short* __restrict__ Ah, const unsigned short* __restrict__ Al,
    unsigned short* __restrict__ Lh, unsigned short* __restrict__ Ll,
    unsigned short* __restrict__ Rh, unsigned short* __restrict__ Rl)
{
  __shared__ float t[32][33];
  __shared__ int sinv[32];
  int b = blockIdx.x, c = threadIdx.x;
  if (b < k){
    int pr = perm[b]; float s = score[pr];
    float v = x[(size_t)pr * 256 + c] * s;
    unsigned short h = f2bf(v);
    xph[(size_t)b * 256 + c] = h;
    xpl[(size_t)b * 256 + c] = f2bf(v - bf2f(h));
    return;
  }
  b -= k;
  if (b < n){
    if (inv[b] < 0){
      float v = x[(size_t)b * 256 + c];
      unsigned short h = f2bf(v);
      xuh[(size_t)b * 256 + c] = h;
      xul[(size_t)b * 256 + c] = f2bf(v - bf2f(h));
    }
    return;
  }
  b -= n;
  if (b < k){
    int r = b, pr = perm[r];
    for (int cc = threadIdx.x; cc < n; cc += 256){
      float v = bf2f(Ah[(size_t)pr * n + cc]);
      if (SRCL) v += bf2f(Al[(size_t)pr * n + cc]);
      if (pr == cc) v += 1.f;
      unsigned short h = f2bf(v);
      Lh[(size_t)r * n + cc] = h;
      if (OUTL) Ll[(size_t)r * n + cc] = f2bf(v - bf2f(h));
    }
    return;
  }
  b -= k;
  int tpr = n >> 5;
  int kt = b / tpr, ct = b - kt * tpr;
  int tx = threadIdx.x & 31, ty = threadIdx.x >> 5;
  if (threadIdx.x < 32) sinv[threadIdx.x] = inv[ct * 32 + threadIdx.x];
#pragma unroll
  for (int i = 0; i < 4; ++i){
    int kl = ty + i * 8;
    size_t src = (size_t)(kt * 32 + kl) * n + ct * 32 + tx;
    float v = bf2f(Ah[src]);
    if (SRCL) v += bf2f(Al[src]);
    t[kl][tx] = v;
  }
  __syncthreads();
#pragma unroll
  for (int i = 0; i < 4; ++i){
    int cl = ty + i * 8;
    int s = sinv[cl];
    if (s >= 0){
      float v = t[tx][cl];
      if (kt * 32 + tx == ct * 32 + cl) v += 1.f;
      unsigned short h = f2bf(v);
      size_t o = (size_t)s * n + kt * 32 + tx;
      Rh[o] = h;
      if (OUTL) Rl[o] = f2bf(v - bf2f(h));
    }
  }
}

// ---------------- pool-1 squaring from ELL (2-bit packed Rb) ----------------
__global__ __launch_bounds__(256) void k_sq1(const int* __restrict__ ell, const int* __restrict__ cnt,
                                             const int* __restrict__ perm,
                                             const unsigned short* __restrict__ Rb2,
                                             unsigned short* __restrict__ A1h,
                                             float* __restrict__ dinv1){
  int r = blockIdx.x;
  int pr = perm[r];
  __shared__ int s_idx[ECAP];
  __shared__ int s_n;
  __shared__ float sred[4];
  if (threadIdx.x == 0) s_n = cnt[pr];
  for (int i = threadIdx.x; i < ECAP; i += 256) s_idx[i] = ell[pr * ECAP + i];
  __syncthreads();
  int n = s_n; if (n > ECAP) n = ECAP;
  int colb = threadIdx.x * 8;
  auto expand = [](unsigned x) -> uint2 {
    uint2 e;
    e.x = (x & 3) | (((x >> 2) & 3) << 8) | (((x >> 4) & 3) << 16) | (((x >> 6) & 3) << 24);
    e.y = ((x >> 8) & 3) | (((x >> 10) & 3) << 8) | (((x >> 12) & 3) << 16) | (((x >> 14) & 3) << 24);
    return e;
  };
  uint2 acc = expand(Rb2[pr * 256 + threadIdx.x]);
  for (int e = 0; e < n; ++e){
    uint2 v = expand(Rb2[s_idx[e] * 256 + threadIdx.x]);
    acc.x += v.x; acc.y += v.y;   // bytewise, no carries (values <=130)
  }
  float fs = 0.f;
  us8_t o;
#pragma unroll
  for (int j = 0; j < 8; ++j){
    unsigned byte = ((j < 4 ? acc.x : acc.y) >> (8 * (j & 3))) & 0xFFu;
    if (colb + j == r) byte = 0;
    float f = (float)byte;
    fs += f;
    o[j] = f2bf(f);
  }
  *(us8_t*)(A1h + (size_t)r * 2048 + colb) = o;
  fs = waveReduceSum(fs);
  int lane = threadIdx.x & 63, wd = threadIdx.x >> 6;
  if (!lane) sred[wd] = fs;
  __syncthreads();
  if (!threadIdx.x)
    dinv1[r] = 1.0f / sqrtf(sred[0] + sred[1] + sred[2] + sred[3] + 2.0f);
}

// ---------------- MFMA GEMM: global_load_lds double-buffered ----------------
// EPI 0: write fp32 partial P[z][M][N] (split-K)
// EPI 2: Cf = dinv[row]*acc
// EPI 4: sv = dinv[row]*acc; Cf = sv; Ch/Cl[col*M+row] = split(sv)  (transposed split)
template<int HAS_AL, int HAS_BL, int HAS_LL, int EPI>
__global__ __launch_bounds__(256) void k_mm(
    const unsigned short* __restrict__ Ah, const unsigned short* __restrict__ Al,
    const unsigned short* __restrict__ Bh, const unsigned short* __restrict__ Bl,
    int M, int N, int K, int KS, float* __restrict__ P,
    float* __restrict__ Cf, unsigned short* __restrict__ Ch, unsigned short* __restrict__ Cl,
    const float* __restrict__ dinv)
{
  constexpr int NARR = 2 + HAS_AL + HAS_BL;
  constexpr int BUF = NARR * 8192;
  __shared__ int4 ldsq[NARR * 512 * 2];
  char* ldsc = (char*)ldsq;

  const int tid = threadIdx.x, lane = tid & 63, wid = tid >> 6;
  const int wm = wid >> 1, wn = wid & 1;
  const int bm = blockIdx.y << 6, bn = blockIdx.x << 6;
  const int z = blockIdx.z;
  const int l15 = lane & 15, l4 = lane >> 4;

  f4_t acc[2][2];
#pragma unroll
  for (int i = 0; i < 2; ++i)
#pragma unroll
    for (int j = 0; j < 2; ++j) acc[i][j] = (f4_t){0.f, 0.f, 0.f, 0.f};

  const size_t rb = (size_t)K * 2;
  const size_t kz = (size_t)z * KS * 2;
  const char* pAh = (const char*)Ah + (size_t)bm * rb;
  const char* pAl = HAS_AL ? (const char*)Al + (size_t)bm * rb : nullptr;
  const char* pBh = (const char*)Bh + (size_t)bn * rb;
  const char* pBl = HAS_BL ? (const char*)Bl + (size_t)bn * rb : nullptr;

  auto stage = [&](int t, int b2){
    char* ldsb = ldsc + b2 * BUF;
    const size_t kb = kz + (size_t)t * 128;
#pragma unroll
    for (int it = 0; it < 2; ++it){
      const int idx = tid + (it << 8);
      const int row = idx >> 3;
      const int kc = ((idx & 7) << 4) ^ ((row & 7) << 4);  // pre-swizzled source col
      const size_t go = (size_t)row * rb + kb + kc;
      const int lo = idx * 16;
      __builtin_amdgcn_global_load_lds((const GAS void*)(pAh + go), (LAS void*)(ldsb + lo), 16, 0, 0);
      __builtin_amdgcn_global_load_lds((const GAS void*)(pBh + go), (LAS void*)(ldsb + 8192 + lo), 16, 0, 0);
      if (HAS_AL)
        __builtin_amdgcn_global_load_lds((const GAS void*)(pAl + go), (LAS void*)(ldsb + 16384 + lo), 16, 0, 0);
      if (HAS_BL)
        __builtin_amdgcn_global_load_lds((const GAS void*)(pBl + go), (LAS void*)(ldsb + (2 + HAS_AL) * 8192 + lo), 16, 0, 0);
    }
  };

  const int T = KS >> 6;
  stage(0, 0);
  int b = 0;
  for (int t = 0; t < T; ++t){
    if (t + 1 < T){
      stage(t + 1, b ^ 1);
      if constexpr (NARR == 2) asm volatile("s_waitcnt vmcnt(4)" ::: "memory");
      else if constexpr (NARR == 3) asm volatile("s_waitcnt vmcnt(6)" ::: "memory");
      else asm volatile("s_waitcnt vmcnt(8)" ::: "memory");
    } else {
      asm volatile("s_waitcnt vmcnt(0)" ::: "memory");
    }
    __syncthreads();
    const char* ldsb = ldsc + b * BUF;
#pragma unroll
    for (int ks = 0; ks < 2; ++ks){
      bf8_t aH[2], aL[2], bH[2], bL[2];
#pragma unroll
      for (int f = 0; f < 2; ++f){
        int ar = wm * 32 + f * 16 + l15;
        int aoff = ar * 128 + (((ks * 64) + (l4 << 4)) ^ ((ar & 7) << 4));
        aH[f] = *(const bf8_t*)(ldsb + aoff);
        if (HAS_AL) aL[f] = *(const bf8_t*)(ldsb + 16384 + aoff);
        int br = wn * 32 + f * 16 + l15;
        int boff = br * 128 + (((ks * 64) + (l4 << 4)) ^ ((br & 7) << 4));
        bH[f] = *(const bf8_t*)(ldsb + 8192 + boff);
        if (HAS_BL) bL[f] = *(const bf8_t*)(ldsb + (2 + HAS_AL) * 8192 + boff);
      }
#pragma unroll
      for (int i = 0; i < 2; ++i)
#pragma unroll
        for (int j = 0; j < 2; ++j){
          acc[i][j] = __builtin_amdgcn_mfma_f32_16x16x32_bf16(aH[i], bH[j], acc[i][j], 0, 0, 0);
          if (HAS_BL) acc[i][j] = __builtin_amdgcn_mfma_f32_16x16x32_bf16(aH[i], bL[j], acc[i][j], 0, 0, 0);
          if (HAS_AL) acc[i][j] = __builtin_amdgcn_mfma_f32_16x16x32_bf16(aL[i], bH[j], acc[i][j], 0, 0, 0);
          if (HAS_LL) acc[i][j] = __builtin_amdgcn_mfma_f32_16x16x32_bf16(aL[i], bL[j], acc[i][j], 0, 0, 0);
        }
    }
    __syncthreads();
    b ^= 1;
  }

  float* Pz = (EPI == 0) ? P + (size_t)z * M * N : nullptr;
#pragma unroll
  for (int i = 0; i < 2; ++i)
#pragma unroll
    for (int j = 0; j < 2; ++j)
#pragma unroll
      for (int r = 0; r < 4; ++r){
        int grow = bm + wm * 32 + i * 16 + l4 * 4 + r;
        int gcol = bn + wn * 32 + j * 16 + l15;
        float v = acc[i][j][r];
        size_t o = (size_t)grow * N + gcol;
        if (EPI == 0){
          Pz[o] = v;
        } else if (EPI == 2){
          Cf[o] = dinv[grow] * v;
        } else { // EPI == 4
          float sv = dinv[grow] * v;
          Cf[o] = sv;
          unsigned short h = f2bf(sv);
          size_t ot = (size_t)gcol * M + grow;
          Ch[ot] = h; Cl[ot] = f2bf(sv - bf2f(h));
        }
      }
}

// ---------------- split-K reduce, wave-per-row, float4 (4 rows per block) ----------------
template<int EPI, int SC>
__global__ __launch_bounds__(256) void k_red(
    const float* __restrict__ P, int Z, int M, int NC,
    const float* __restrict__ dinv, const float* __restrict__ Zs,
    const float* __restrict__ bias,
    float* __restrict__ Of, unsigned short* __restrict__ Oh, unsigned short* __restrict__ Ol,
    float* __restrict__ dout, int relu,
    const float* __restrict__ scw, float* __restrict__ score,
    const float* __restrict__ res, const int* __restrict__ permsel)
{
  int w = threadIdx.x >> 6, lane = threadIdx.x & 63;
  int row = blockIdx.x * 4 + w;
  int prow = (EPI == 4) ? permsel[row] : 0;
  float di = (EPI != 3) ? dinv[row] : 0.f;
  float rsum = 0.f, o_d = 0.f, o_q = 0.f;
  for (int c0 = lane * 4; c0 < NC; c0 += 256){
    size_t o = (size_t)row * NC + c0;
    f4_t s = *(const f4_t*)(P + o);
    for (int zz = 1; zz < Z; ++zz) s += *(const f4_t*)(P + (size_t)zz * M * NC + o);
    if (EPI == 2){
      f4_t z4 = *(const f4_t*)(Zs + o);
      f4_t b4 = *(const f4_t*)(bias + c0);
      f4_t out;
#pragma unroll
      for (int j = 0; j < 4; ++j){
        float v = di * (s[j] + 2.0f * z4[j]) + b4[j];
        if (relu) v = fmaxf(v, 0.f);
        out[j] = v;
      }
      *(f4_t*)(Of + o) = out;
      if (SC){
        f4_t w4 = *(const f4_t*)(scw + c0);
#pragma unroll
        for (int j = 0; j < 4; ++j){ o_d += out[j] * w4[j]; o_q += w4[j] * w4[j]; }
      }
    } else if (EPI == 3){
      us4_t h4, l4v;
#pragma unroll
      for (int j = 0; j < 4; ++j){
        float v = (c0 + j == row) ? 0.f : s[j];
        unsigned short h = f2bf(v);
        h4[j] = h; l4v[j] = f2bf(v - bf2f(h));
        rsum += v;
      }
      *(us4_t*)(Oh + o) = h4;
      *(us4_t*)(Ol + o) = l4v;
    } else { // EPI == 4
      f4_t z4 = *(const f4_t*)(Zs + o);
      f4_t b4 = *(const f4_t*)(bias + c0);
      f4_t r4 = *(const f4_t*)(res + (size_t)prow * NC + c0);
      us4_t h4, l4v;
#pragma unroll
      for (int j = 0; j < 4; ++j){
        float v = di * (s[j] + 2.0f * z4[j]) + b4[j];
        if (relu) v = fmaxf(v, 0.f);
        float comb = r4[j] + v;
        unsigned short h = f2bf(comb);
        h4[j] = h; l4v[j] = f2bf(comb - bf2f(h));
      }
      size_t od = (size_t)prow * NC + c0;
      *(us4_t*)(Oh + od) = h4;
      *(us4_t*)(Ol + od) = l4v;
    }
  }
  if (EPI == 3){
    rsum = waveReduceSum(rsum);
    if (!lane) dout[row] = 1.0f / sqrtf(rsum + 2.0f);
  }
  if (SC){
    o_d = waveReduceSum(o_d);
    o_q = waveReduceSum(o_q);
    if (!lane) score[row] = tanhf(o_d / sqrtf(o_q));
  }
}

// ---------------- topk (stable descending rank) ----------------
__global__ void k_topk(const float* __restrict__ score, int n, int k,
                       int* __restrict__ perm, int* __restrict__ inv){
  int i = blockIdx.x; float si = score[i];
  int cnt = 0;
  for (int j = threadIdx.x; j < n; j += 256){
    float sj = score[j];
    if (sj > si || (sj == si && j < i)) cnt++;
  }
#pragma unroll
  for (int off = 32; off > 0; off >>= 1) cnt += __shfl_down(cnt, off);
  __shared__ int sh[4];
  int lane = threadIdx.x & 63, wid = threadIdx.x >> 6;
  if (lane == 0) sh[wid] = cnt;
  __syncthreads();
  if (threadIdx.x == 0){
    int rank = sh[0] + sh[1] + sh[2] + sh[3];
    if (rank < k){ perm[rank] = i; inv[i] = rank; }
    else inv[i] = -1;
  }
}

// ---------------- host orchestration ----------------
extern "C" void kernel_launch(void* const* d_in, const int* in_sizes, int n_in,
                              void* d_out, int out_size, void* d_ws, size_t ws_size,
                              hipStream_t stream){
  (void)in_sizes; (void)n_in; (void)out_size;
  const float* x_in = (const float*)d_in[0];
  const int*   ei   = (const int*)d_in[1];
  const float* dW0 = (const float*)d_in[2];
  const float* dW1 = (const float*)d_in[3];
  const float* dW2 = (const float*)d_in[4];
  const float* dW3 = (const float*)d_in[5];
  const float* db0 = (const float*)d_in[6];
  const float* db1 = (const float*)d_in[7];
  const float* db2 = (const float*)d_in[8];
  const float* db3 = (const float*)d_in[9];
  const float* pw0 = (const float*)d_in[10];
  const float* pw1 = (const float*)d_in[11];
  const float* pw2 = (const float*)d_in[12];
  const float* uW0 = (const float*)d_in[13];
  const float* uW1 = (const float*)d_in[14];
  const float* uW2 = (const float*)d_in[15];
  const float* ub0 = (const float*)d_in[16];
  const float* ub1 = (const float*)d_in[17];
  const float* ub2 = (const float*)d_in[18];

  char* p = (char*)d_ws;
  auto alloc = [&](size_t nbytes) -> void* {
    void* q = (void*)p; p += (nbytes + 255) & ~(size_t)255; return q;
  };
  unsigned* bits = (unsigned*)alloc((size_t)4096 * 128 * 4);
  int* ell = (int*)alloc((size_t)4096 * ECAP * 4);
  int* cnt = (int*)alloc(4096 * 4);
  int* inv1 = (int*)alloc(4096 * 4);
  int* inv2 = (int*)alloc(2048 * 4);
  int* inv3 = (int*)alloc(1024 * 4);
  unsigned short* Rb2 = (unsigned short*)alloc((size_t)4096 * 256 * 2);  // 2-bit packed
  float* Pp = (float*)alloc((size_t)8 * 1024 * 1024);   // split-K partials / G buffer
  unsigned short* A1h = (unsigned short*)alloc((size_t)2048 * 2048 * 2);
  unsigned short* A2h = (unsigned short*)alloc((size_t)1024 * 1024 * 2);
  unsigned short* A2l = (unsigned short*)alloc((size_t)1024 * 1024 * 2);
  unsigned short* A3h = (unsigned short*)alloc((size_t)512 * 512 * 2);
  unsigned short* A3l = (unsigned short*)alloc((size_t)512 * 512 * 2);
  unsigned short* Lb2h = (unsigned short*)alloc((size_t)1024 * 2048 * 2);
  unsigned short* Rt2h = (unsigned short*)alloc((size_t)1024 * 2048 * 2);
  unsigned short* Lb3h = (unsigned short*)alloc((size_t)512 * 1024 * 2);
  unsigned short* Lb3l = (unsigned short*)alloc((size_t)512 * 1024 * 2);
  unsigned short* Rt3h = (unsigned short*)alloc((size_t)512 * 1024 * 2);
  unsigned short* Rt3l = (unsigned short*)alloc((size_t)512 * 1024 * 2);
  unsigned short* xinh = (unsigned short*)alloc((size_t)4096 * 512 * 2);
  unsigned short* xinl = (unsigned short*)alloc((size_t)4096 * 512 * 2);
  float* x0 = (float*)alloc((size_t)4096 * HID * 4);
  float* x1 = (float*)alloc((size_t)2048 * HID * 4);
  float* x2 = (float*)alloc((size_t)1024 * HID * 4);
  unsigned short* xu1h = (unsigned short*)alloc((size_t)4096 * HID * 2);
  unsigned short* xu1l = (unsigned short*)alloc((size_t)4096 * HID * 2);
  unsigned short* xu2h = (unsigned short*)alloc((size_t)2048 * HID * 2);
  unsigned short* xu2l = (unsigned short*)alloc((size_t)2048 * HID * 2);
  unsigned short* xu3h = (unsigned short*)alloc((size_t)1024 * HID * 2);
  unsigned short* xu3l = (unsigned short*)alloc((size_t)1024 * HID * 2);
  unsigned short* xph = (unsigned short*)alloc((size_t)2048 * HID * 2);
  unsigned short* xpl = (unsigned short*)alloc((size_t)2048 * HID * 2);
  unsigned short* W0th = (unsigned short*)alloc((size_t)256 * 512 * 2);
  unsigned short* W0tl = (unsigned short*)alloc((size_t)256 * 512 * 2);
  unsigned short* W5th = (unsigned short*)alloc((size_t)5 * 256 * 256 * 2);
  unsigned short* W5tl = (unsigned short*)alloc((size_t)5 * 256 * 256 * 2);
  unsigned short* W2th = (unsigned short*)alloc((size_t)64 * 256 * 2);
  unsigned short* W2tl = (unsigned short*)alloc((size_t)64 * 256 * 2);
  float* Zs  = (float*)alloc((size_t)4096 * HID * 4);
  unsigned short* ZsTh = (unsigned short*)alloc((size_t)256 * 2048 * 2);
  unsigned short* ZsTl = (unsigned short*)alloc((size_t)256 * 2048 * 2);
  float* dinv0 = (float*)alloc(4096 * 4);
  float* dinv1 = (float*)alloc(2048 * 4);
  float* dinv2 = (float*)alloc(1024 * 4);
  float* dinv3 = (float*)alloc(512 * 4);
  float* score = (float*)alloc(4096 * 4);
  int* perm1 = (int*)alloc(2048 * 4);
  int* perm2 = (int*)alloc(1024 * 4);
  int* perm3 = (int*)alloc(512 * 4);
  if ((size_t)(p - (char*)d_ws) > ws_size) return;

  // 1: prep (bits zero + x split + all weight tsplits)
  k_prep<<<2640, 256, 0, stream>>>(x_in, dW0, dW1, dW2, dW3, uW0, uW1, uW2, bits,
                                   xinh, xinl, W0th, W0tl, W5th, W5tl, W2th, W2tl);
  // 2-3: graph build
  k_build_bits<<<EE / 256, 256, 0, stream>>>(ei, bits);
  k_ell<<<4096, 128, 0, stream>>>(bits, ell, cnt, dinv0);

  // 4-5: conv0 (+ pool-1 score fused)
  { dim3 g(4, 64);
    k_mm<1,1,0,2><<<g, 256, 0, stream>>>(xinh, xinl, W0th, W0tl, 4096, HID, IN_DIM, IN_DIM,
                                         nullptr, Zs, nullptr, nullptr, dinv0); }
  k_spmm_ell<256,1,1><<<4096, 256, 0, stream>>>(ell, cnt, Zs, dinv0, db0, x0, pw0, score);

  // 6-8: pool 1 (4096 -> 2048)
  k_topk<<<4096, 256, 0, stream>>>(score, 4096, 2048, perm1, inv1);
  k_pool_build<<<10240, 256, 0, stream>>>(x0, score, perm1, inv1, ell, cnt,
                                          xph, xpl, Rb2, xu1h, xu1l);
  k_sq1<<<2048, 256, 0, stream>>>(ell, cnt, perm1, Rb2, A1h, dinv1);
  // 9-11: conv1 (g1 EPI2; A1@Zs factored through A0: gG + gY)
  { dim3 g(4, 32);
    k_mm<1,1,0,2><<<g, 256, 0, stream>>>(xph, xpl, W5th, W5tl, 2048, HID, HID, HID,
                                         nullptr, Zs, nullptr, nullptr, dinv1); }
  k_gG<<<4096, 256, 0, stream>>>(ell, cnt, inv1, Zs, Pp);
  k_gY<0><<<2048, 256, 0, stream>>>(ell, cnt, perm1, bits, Pp, Zs, dinv1, db1,
                                    x1, nullptr, nullptr, pw1, score, nullptr);

  // 12-15: pool 2 (2048 -> 1024)
  k_topk<<<2048, 256, 0, stream>>>(score, 2048, 1024, perm2, inv2);
  k_pp<0,0><<<8192, 256, 0, stream>>>(x1, score, perm2, inv2, 2048, 1024,
                                      xph, xpl, xu2h, xu2l, A1h, nullptr,
                                      Lb2h, nullptr, Rt2h, nullptr);
  { dim3 g(16, 16, 2);
    k_mm<0,0,0,0><<<g, 256, 0, stream>>>(Lb2h, nullptr, Rt2h, nullptr, 1024, 1024, 2048, 1024,
                                         Pp, nullptr, nullptr, nullptr, nullptr); }
  k_red<3,0><<<256, 256, 0, stream>>>(Pp, 2, 1024, 1024, nullptr, nullptr, nullptr,
                                      nullptr, A2h, A2l, dinv2, 0, nullptr, nullptr, nullptr, nullptr);
  // 16-18: conv2
  { dim3 g(4, 16);
    k_mm<1,1,0,4><<<g, 256, 0, stream>>>(xph, xpl, W5th + 65536, W5tl + 65536, 1024, HID, HID, HID,
                                         nullptr, Zs, ZsTh, ZsTl, dinv2); }
  { dim3 g(4, 16, 4);
    k_mm<1,1,0,0><<<g, 256, 0, stream>>>(A2h, A2l, ZsTh, ZsTl, 1024, HID, 1024, 256,
                                         Pp, nullptr, nullptr, nullptr, nullptr); }
  k_red<2,1><<<256, 256, 0, stream>>>(Pp, 4, 1024, 256, dinv2, Zs, db2,
                                      x2, nullptr, nullptr, nullptr, 1, pw2, score, nullptr, nullptr);

  // 19-22: pool 3 (1024 -> 512)
  k_topk<<<1024, 256, 0, stream>>>(score, 1024, 512, perm3, inv3);
  k_pp<1,1><<<3072, 256, 0, stream>>>(x2, score, perm3, inv3, 1024, 512,
                                      xph, xpl, xu3h, xu3l, A2h, A2l,
                                      Lb3h, Lb3l, Rt3h, Rt3l);
  { dim3 g(8, 8, 4);
    k_mm<1,1,1,0><<<g, 256, 0, stream>>>(Lb3h, Lb3l, Rt3h, Rt3l, 512, 512, 1024, 256,
                                         Pp, nullptr, nullptr, nullptr, nullptr); }
  k_red<3,0><<<128, 256, 0, stream>>>(Pp, 4, 512, 512, nullptr, nullptr, nullptr,
                                      nullptr, A3h, A3l, dinv3, 0, nullptr, nullptr, nullptr, nullptr);
  // 23-25: conv3 -> scatter into xu3
  { dim3 g(4, 8);
    k_mm<1,1,0,4><<<g, 256, 0, stream>>>(xph, xpl, W5th + 2 * 65536, W5tl + 2 * 65536, 512, HID, HID, HID,
                                         nullptr, Zs, ZsTh, ZsTl, dinv3); }
  { dim3 g(4, 8, 4);
    k_mm<1,1,0,0><<<g, 256, 0, stream>>>(A3h, A3l, ZsTh, ZsTl, 512, HID, 512, 128,
                                         Pp, nullptr, nullptr, nullptr, nullptr); }
  k_red<4,0><<<128, 256, 0, stream>>>(Pp, 4, 512, 256, dinv3, Zs, db3,
                                      nullptr, xu3h, xu3l, nullptr, 1, nullptr, nullptr, x2, perm3);

  // 26-28: up0 -> scatter into xu2
  { dim3 g(4, 16);
    k_mm<1,1,0,4><<<g, 256, 0, stream>>>(xu3h, xu3l, W5th + 3 * 65536, W5tl + 3 * 65536, 1024, HID, HID, HID,
                                         nullptr, Zs, ZsTh, ZsTl, dinv2); }
  { dim3 g(4, 16, 4);
    k_mm<1,1,0,0><<<g, 256, 0, stream>>>(A2h, A2l, ZsTh, ZsTl, 1024, HID, 1024, 256,
                                         Pp, nullptr, nullptr, nullptr, nullptr); }
  k_red<4,0><<<256, 256, 0, stream>>>(Pp, 4, 1024, 256, dinv2, Zs, ub0,
                                      nullptr, xu2h, xu2l, nullptr, 1, nullptr, nullptr, x1, perm2);

  // 29-31: up1 (A1@Zs factored) -> scatter into xu1
  { dim3 g(4, 32);
    k_mm<1,1,0,2><<<g, 256, 0, stream>>>(xu2h, xu2l, W5th + 4 * 65536, W5tl + 4 * 65536, 2048, HID, HID, HID,
                                         nullptr, Zs, nullptr, nullptr, dinv1); }
  k_gG<<<4096, 256, 0, stream>>>(ell, cnt, inv1, Zs, Pp);
  k_gY<1><<<2048, 256, 0, stream>>>(ell, cnt, perm1, bits, Pp, Zs, dinv1, ub1,
                                    nullptr, xu1h, xu1l, nullptr, nullptr, x0);

  // 32-33: up2 (A0 sparse, Cout=64, no relu)
  { dim3 g(1, 64);
    k_mm<1,1,0,2><<<g, 256, 0, stream>>>(xu1h, xu1l, W2th, W2tl, 4096, OUT_DIM, HID, HID,
                                         nullptr, Zs, nullptr, nullptr, dinv0); }
  k_spmm_ell<64,0,0><<<4096, 256, 0, stream>>>(ell, cnt, Zs, dinv0, ub2, (float*)d_out, nullptr, nullptr);
}

// Round 10
// 228.193 us; speedup vs baseline: 1.0568x; 1.0568x over previous
//
#include <hip/hip_runtime.h>
#include <math.h>

#define NN 4096
#define EE 131072
#define IN_DIM 512
#define HID 256
#define OUT_DIM 64
#define ECAP 128

typedef __attribute__((ext_vector_type(8))) short bf8_t;
typedef __attribute__((ext_vector_type(4))) float f4_t;
typedef __attribute__((ext_vector_type(8))) unsigned short us8_t;
typedef __attribute__((ext_vector_type(4))) unsigned short us4_t;

#define GAS __attribute__((address_space(1)))
#define LAS __attribute__((address_space(3)))

// ---------------- bf16 helpers (RNE) ----------------
__device__ __forceinline__ unsigned short f2bf(float v){
  union { float f; unsigned u; } x; x.f = v;
  unsigned r = x.u + 0x7fffu + ((x.u >> 16) & 1u);
  return (unsigned short)(r >> 16);
}
__device__ __forceinline__ float bf2f(unsigned short h){
  union { float f; unsigned u; } x; x.u = ((unsigned)h) << 16;
  return x.f;
}

__device__ __forceinline__ float waveReduceSum(float v){
#pragma unroll
  for (int off = 32; off > 0; off >>= 1) v += __shfl_down(v, off);
  return v;
}

// ---------------- mega-prep: zero bits + split x_in + transpose-split all weights ----------------
__global__ __launch_bounds__(256) void k_prep(
    const float* __restrict__ x_in, const float* __restrict__ dW0,
    const float* __restrict__ dW1, const float* __restrict__ dW2,
    const float* __restrict__ dW3, const float* __restrict__ uW0,
    const float* __restrict__ uW1, const float* __restrict__ uW2,
    unsigned* __restrict__ bits,
    unsigned short* __restrict__ xinh, unsigned short* __restrict__ xinl,
    unsigned short* __restrict__ W0th, unsigned short* __restrict__ W0tl,
    unsigned short* __restrict__ W5th, unsigned short* __restrict__ W5tl,
    unsigned short* __restrict__ W2th, unsigned short* __restrict__ W2tl)
{
  int b = blockIdx.x;
  if (b < 128){                       // zero 2MB bit-adjacency
    int base = b * 4096 + threadIdx.x;
#pragma unroll
    for (int i = 0; i < 16; ++i) bits[base + i * 256] = 0;
    return;
  }
  b -= 128;
  if (b < 2048){                      // split x_in (4096x512 fp32 -> bf16 hi/lo)
    int i0 = b * 1024 + threadIdx.x;
#pragma unroll
    for (int i = 0; i < 4; ++i){
      int idx = i0 + i * 256;
      float v = x_in[idx];
      unsigned short h = f2bf(v);
      xinh[idx] = h; xinl[idx] = f2bf(v - bf2f(h));
    }
    return;
  }
  b -= 2048;
  const float* X; unsigned short *Th, *Tl; int R, C, tile;
  if (b < 128){ X = dW0; Th = W0th; Tl = W0tl; R = 512; C = 256; tile = b; }
  else if (b < 448){
    int t2 = b - 128; int z = t2 >> 6; int rem = t2 & 63;
    const float* ws[5] = {dW1, dW2, dW3, uW0, uW1};
    X = ws[z]; Th = W5th + (size_t)z * 65536; Tl = W5tl + (size_t)z * 65536;
    R = 256; C = 256; tile = rem;
  } else { X = uW2; Th = W2th; Tl = W2tl; R = 256; C = 64; tile = b - 448; }
  int tpr = C >> 5;
  int bx = (tile % tpr) * 32, by = (tile / tpr) * 32;
  __shared__ float t[32][33];
  int tx = threadIdx.x & 31, ty = threadIdx.x >> 5;
#pragma unroll
  for (int i = 0; i < 4; ++i)
    t[ty + i * 8][tx] = X[(size_t)(by + ty + i * 8) * C + bx + tx];
  __syncthreads();
#pragma unroll
  for (int i = 0; i < 4; ++i){
    float v = t[tx][ty + i * 8];
    unsigned short h = f2bf(v);
    size_t o = (size_t)(bx + ty + i * 8) * R + by + tx;
    Th[o] = h; Tl[o] = f2bf(v - bf2f(h));
  }
}

// ---------------- graph build: bitmask + ELL ----------------
__global__ void k_build_bits(const int* __restrict__ ei, unsigned* __restrict__ bits){
  int e = blockIdx.x * blockDim.x + threadIdx.x;
  if (e < EE){
    int r = ei[e], c = ei[EE + e];
    atomicOr(&bits[r * 128 + (c >> 5)], 1u << (c & 31));
  }
}

__global__ __launch_bounds__(128) void k_ell(const unsigned* __restrict__ bits,
                                             int* __restrict__ ell, int* __restrict__ cnt,
                                             float* __restrict__ dinv){
  int r = blockIdx.x, t = threadIdx.x;
  unsigned w = bits[r * 128 + t];
  int c = __popc(w);
  __shared__ int sc[128];
  sc[t] = c; __syncthreads();
  for (int off = 1; off < 128; off <<= 1){
    int a = sc[t], b = (t >= off) ? sc[t - off] : 0;
    __syncthreads(); sc[t] = a + b; __syncthreads();
  }
  int total = sc[127];
  int pos = sc[t] - c;
  int base = r * ECAP;
  while (w){
    int b = __ffs(w) - 1; w &= w - 1;
    if (pos < ECAP) ell[base + pos] = t * 32 + b;
    pos++;
  }
  if (t == 0){
    cnt[r] = (total < ECAP) ? total : ECAP;
    dinv[r] = 1.0f / sqrtf((float)total + 2.0f);
  }
}

// ---------------- fused SpMM (ELL, values==1) + GCN epilogue (+ optional score) ----------------
template<int NCOLS, int RELU, int SC>
__global__ __launch_bounds__(256) void k_spmm_ell(
    const int* __restrict__ ell, const int* __restrict__ cnt,
    const float* __restrict__ Zs, const float* __restrict__ dinv,
    const float* __restrict__ bias, float* __restrict__ out,
    const float* __restrict__ scw, float* __restrict__ score)
{
  int r = blockIdx.x;
  __shared__ int s_idx[ECAP];
  __shared__ int s_n;
  __shared__ float sh[4 * NCOLS];
  __shared__ float sd[4], sq[4];
  if (threadIdx.x == 0) s_n = cnt[r];
  for (int i = threadIdx.x; i < ECAP; i += 256) s_idx[i] = ell[r * ECAP + i];
  __syncthreads();
  int n = s_n; if (n > ECAP) n = ECAP;
  int wv = threadIdx.x >> 6, lane = threadIdx.x & 63;
  if (NCOLS == 256){
    f4_t acc = (f4_t){0.f, 0.f, 0.f, 0.f};
    for (int e = wv; e < n; e += 4){
      const f4_t* row = (const f4_t*)(Zs + (size_t)s_idx[e] * 256);
      acc += row[lane];
    }
    ((f4_t*)(sh + wv * 256))[lane] = acc;
  } else {
    float acc = 0.f;
    for (int e = wv; e < n; e += 4)
      acc += Zs[(size_t)s_idx[e] * 64 + lane];
    sh[wv * 64 + lane] = acc;
  }
  __syncthreads();
  int t = threadIdx.x;
  float o = 0.f;
  if (t < NCOLS){
    float y = sh[t] + sh[NCOLS + t] + sh[2 * NCOLS + t] + sh[3 * NCOLS + t];
    float z = Zs[(size_t)r * NCOLS + t];
    o = dinv[r] * (y + 2.0f * z) + bias[t];
    if (RELU) o = fmaxf(o, 0.f);
    out[(size_t)r * NCOLS + t] = o;
  }
  if (SC){
    float w = scw[t];
    float d = waveReduceSum(o * w);
    float q = waveReduceSum(w * w);
    if (!lane){ sd[wv] = d; sq[wv] = q; }
    __syncthreads();
    if (!t) score[r] = tanhf((sd[0] + sd[1] + sd[2] + sd[3]) / sqrtf(sq[0] + sq[1] + sq[2] + sq[3]));
  }
}

// ---------------- pool1: pool_x2 + build_Rb (2-bit packed) + xu1 fill ----------------
__global__ __launch_bounds__(256) void k_pool_build(
    const float* __restrict__ x0, const float* __restrict__ score,
    const int* __restrict__ perm1, const int* __restrict__ inv1,
    const int* __restrict__ ell, const int* __restrict__ cnt,
    unsigned short* __restrict__ xph, unsigned short* __restrict__ xpl,
    unsigned short* __restrict__ Rb2,
    unsigned short* __restrict__ xu1h, unsigned short* __restrict__ xu1l)
{
  int b = blockIdx.x;
  if (b < 2048){                           // gated pooled features
    int pr = perm1[b]; float s = score[pr];
    int c = threadIdx.x;
    float v = x0[(size_t)pr * 256 + c] * s;
    unsigned short h = f2bf(v);
    xph[(size_t)b * 256 + c] = h;
    xpl[(size_t)b * 256 + c] = f2bf(v - bf2f(h));
    return;
  }
  if (b < 6144){                           // Rb2[k]: 2-bit packed (A0+I)[k][perm1[s]]
    int k = b - 2048;
    __shared__ unsigned char row[2048];
    for (int i = threadIdx.x; i < 512; i += 256) ((int*)row)[i] = 0;
    __syncthreads();
    int n = cnt[k];
    for (int e = threadIdx.x; e < n; e += 256){
      int s = inv1[ell[k * ECAP + e]];
      if (s >= 0) row[s] = 1;
    }
    __syncthreads();
    if (threadIdx.x == 0){
      int sk = inv1[k];
      if (sk >= 0) row[sk] += 1;
    }
    __syncthreads();
    unsigned w = 0;
#pragma unroll
    for (int j = 0; j < 8; ++j) w |= ((unsigned)row[(threadIdx.x << 3) + j]) << (2 * j);
    Rb2[k * 256 + threadIdx.x] = (unsigned short)w;
    return;
  }
  int r = b - 6144;                        // xu1 fill: non-selected rows = x0
  if (inv1[r] < 0){
    int c = threadIdx.x;
    float v = x0[(size_t)r * 256 + c];
    unsigned short h = f2bf(v);
    xu1h[(size_t)r * 256 + c] = h;
    xu1l[(size_t)r * 256 + c] = f2bf(v - bf2f(h));
  }
}

// ---------------- pool2/3 prep: pooled-x + xu fill + L row-gather(+I) + transpose-gather(+I) ----------------
template<int SRCL, int OUTL>
__global__ __launch_bounds__(256) void k_pp(
    const float* __restrict__ x, const float* __restrict__ score,
    const int* __restrict__ perm, const int* __restrict__ inv, int n, int k,
    unsigned short* __restrict__ xph, unsigned short* __restrict__ xpl,
    unsigned short* __restrict__ xuh, unsigned short* __restrict__ xul,
    const unsigned short* __restrict__ Ah, const unsigned short* __restrict__ Al,
    unsigned short* __restrict__ Lh, unsigned short* __restrict__ Ll,
    unsigned short* __restrict__ Rh, unsigned short* __restrict__ Rl)
{
  __shared__ float t[32][33];
  __shared__ int sinv[32];
  int b = blockIdx.x, c = threadIdx.x;
  if (b < k){
    int pr = perm[b]; float s = score[pr];
    float v = x[(size_t)pr * 256 + c] * s;
    unsigned short h = f2bf(v);
    xph[(size_t)b * 256 + c] = h;
    xpl[(size_t)b * 256 + c] = f2bf(v - bf2f(h));
    return;
  }
  b -= k;
  if (b < n){
    if (inv[b] < 0){
      float v = x[(size_t)b * 256 + c];
      unsigned short h = f2bf(v);
      xuh[(size_t)b * 256 + c] = h;
      xul[(size_t)b * 256 + c] = f2bf(v - bf2f(h));
    }
    return;
  }
  b -= n;
  if (b < k){
    int r = b, pr = perm[r];
    for (int cc = threadIdx.x; cc < n; cc += 256){
      float v = bf2f(Ah[(size_t)pr * n + cc]);
      if (SRCL) v += bf2f(Al[(size_t)pr * n + cc]);
      if (pr == cc) v += 1.f;
      unsigned short h = f2bf(v);
      Lh[(size_t)r * n + cc] = h;
      if (OUTL) Ll[(size_t)r * n + cc] = f2bf(v - bf2f(h));
    }
    return;
  }
  b -= k;
  int tpr = n >> 5;
  int kt = b / tpr, ct = b - kt * tpr;
  int tx = threadIdx.x & 31, ty = threadIdx.x >> 5;
  if (threadIdx.x < 32) sinv[threadIdx.x] = inv[ct * 32 + threadIdx.x];
#pragma unroll
  for (int i = 0; i < 4; ++i){
    int kl = ty + i * 8;
    size_t src = (size_t)(kt * 32 + kl) * n + ct * 32 + tx;
    float v = bf2f(Ah[src]);
    if (SRCL) v += bf2f(Al[src]);
    t[kl][tx] = v;
  }
  __syncthreads();
#pragma unroll
  for (int i = 0; i < 4; ++i){
    int cl = ty + i * 8;
    int s = sinv[cl];
    if (s >= 0){
      float v = t[tx][cl];
      if (kt * 32 + tx == ct * 32 + cl) v += 1.f;
      unsigned short h = f2bf(v);
      size_t o = (size_t)s * n + kt * 32 + tx;
      Rh[o] = h;
      if (OUTL) Rl[o] = f2bf(v - bf2f(h));
    }
  }
}

// ---------------- pool-1 squaring from ELL (2-bit packed Rb) ----------------
__global__ __launch_bounds__(256) void k_sq1(const int* __restrict__ ell, const int* __restrict__ cnt,
                                             const int* __restrict__ perm,
                                             const unsigned short* __restrict__ Rb2,
                                             unsigned short* __restrict__ A1h,
                                             float* __restrict__ dinv1){
  int r = blockIdx.x;
  int pr = perm[r];
  __shared__ int s_idx[ECAP];
  __shared__ int s_n;
  __shared__ float sred[4];
  if (threadIdx.x == 0) s_n = cnt[pr];
  for (int i = threadIdx.x; i < ECAP; i += 256) s_idx[i] = ell[pr * ECAP + i];
  __syncthreads();
  int n = s_n; if (n > ECAP) n = ECAP;
  int colb = threadIdx.x * 8;
  auto expand = [](unsigned x) -> uint2 {
    uint2 e;
    e.x = (x & 3) | (((x >> 2) & 3) << 8) | (((x >> 4) & 3) << 16) | (((x >> 6) & 3) << 24);
    e.y = ((x >> 8) & 3) | (((x >> 10) & 3) << 8) | (((x >> 12) & 3) << 16) | (((x >> 14) & 3) << 24);
    return e;
  };
  uint2 acc = expand(Rb2[pr * 256 + threadIdx.x]);
  for (int e = 0; e < n; ++e){
    uint2 v = expand(Rb2[s_idx[e] * 256 + threadIdx.x]);
    acc.x += v.x; acc.y += v.y;   // bytewise, no carries (values <=130)
  }
  float fs = 0.f;
  us8_t o;
#pragma unroll
  for (int j = 0; j < 8; ++j){
    unsigned byte = ((j < 4 ? acc.x : acc.y) >> (8 * (j & 3))) & 0xFFu;
    if (colb + j == r) byte = 0;
    float f = (float)byte;
    fs += f;
    o[j] = f2bf(f);
  }
  *(us8_t*)(A1h + (size_t)r * 2048 + colb) = o;
  fs = waveReduceSum(fs);
  int lane = threadIdx.x & 63, wd = threadIdx.x >> 6;
  if (!lane) sred[wd] = fs;
  __syncthreads();
  if (!threadIdx.x)
    dinv1[r] = 1.0f / sqrtf(sred[0] + sred[1] + sred[2] + sred[3] + 2.0f);
}

// ---------------- MFMA GEMM: global_load_lds dbuf + XCD-swizzled blocks ----------------
// EPI 0: write fp32 partial P[z][M][N] (split-K)
// EPI 2: Cf = dinv[row]*acc
// EPI 4: sv = dinv[row]*acc; Cf = sv; Ch/Cl[col*M+row] = split(sv)  (transposed split)
template<int HAS_AL, int HAS_BL, int HAS_LL, int EPI>
__global__ __launch_bounds__(256) void k_mm(
    const unsigned short* __restrict__ Ah, const unsigned short* __restrict__ Al,
    const unsigned short* __restrict__ Bh, const unsigned short* __restrict__ Bl,
    int M, int N, int K, int KS, float* __restrict__ P,
    float* __restrict__ Cf, unsigned short* __restrict__ Ch, unsigned short* __restrict__ Cl,
    const float* __restrict__ dinv)
{
  constexpr int NARR = 2 + HAS_AL + HAS_BL;
  constexpr int BUF = NARR * 8192;
  __shared__ int4 ldsq[NARR * 512 * 2];
  char* ldsc = (char*)ldsq;

  const int tid = threadIdx.x, lane = tid & 63, wid = tid >> 6;
  const int wm = wid >> 1, wn = wid & 1;
  // XCD-aware bijective swizzle (grid sizes are all multiples of 8):
  // hw-consecutive blocks land on different XCDs; remap so each XCD gets a
  // contiguous work-chunk (x fastest -> same-y blocks share the A-panel).
  const int nbx = gridDim.x, nby = gridDim.y;
  const int tot = nbx * nby * gridDim.z;
  int id = blockIdx.x + nbx * (blockIdx.y + nby * blockIdx.z);
  if ((tot & 7) == 0) id = (id & 7) * (tot >> 3) + (id >> 3);
  const int sx = id % nbx; int remq = id / nbx;
  const int sy = remq % nby;
  const int bm = sy << 6, bn = sx << 6;
  const int z = remq / nby;
  const int l15 = lane & 15, l4 = lane >> 4;

  f4_t acc[2][2];
#pragma unroll
  for (int i = 0; i < 2; ++i)
#pragma unroll
    for (int j = 0; j < 2; ++j) acc[i][j] = (f4_t){0.f, 0.f, 0.f, 0.f};

  const size_t rb = (size_t)K * 2;
  const size_t kz = (size_t)z * KS * 2;
  const char* pAh = (const char*)Ah + (size_t)bm * rb;
  const char* pAl = HAS_AL ? (const char*)Al + (size_t)bm * rb : nullptr;
  const char* pBh = (const char*)Bh + (size_t)bn * rb;
  const char* pBl = HAS_BL ? (const char*)Bl + (size_t)bn * rb : nullptr;

  auto stage = [&](int t, int b2){
    char* ldsb = ldsc + b2 * BUF;
    const size_t kb = kz + (size_t)t * 128;
#pragma unroll
    for (int it = 0; it < 2; ++it){
      const int idx = tid + (it << 8);
      const int row = idx >> 3;
      const int kc = ((idx & 7) << 4) ^ ((row & 7) << 4);  // pre-swizzled source col
      const size_t go = (size_t)row * rb + kb + kc;
      const int lo = idx * 16;
      __builtin_amdgcn_global_load_lds((const GAS void*)(pAh + go), (LAS void*)(ldsb + lo), 16, 0, 0);
      __builtin_amdgcn_global_load_lds((const GAS void*)(pBh + go), (LAS void*)(ldsb + 8192 + lo), 16, 0, 0);
      if (HAS_AL)
        __builtin_amdgcn_global_load_lds((const GAS void*)(pAl + go), (LAS void*)(ldsb + 16384 + lo), 16, 0, 0);
      if (HAS_BL)
        __builtin_amdgcn_global_load_lds((const GAS void*)(pBl + go), (LAS void*)(ldsb + (2 + HAS_AL) * 8192 + lo), 16, 0, 0);
    }
  };

  const int T = KS >> 6;
  stage(0, 0);
  int b = 0;
  for (int t = 0; t < T; ++t){
    if (t + 1 < T){
      stage(t + 1, b ^ 1);
      if constexpr (NARR == 2) asm volatile("s_waitcnt vmcnt(4)" ::: "memory");
      else if constexpr (NARR == 3) asm volatile("s_waitcnt vmcnt(6)" ::: "memory");
      else asm volatile("s_waitcnt vmcnt(8)" ::: "memory");
    } else {
      asm volatile("s_waitcnt vmcnt(0)" ::: "memory");
    }
    __syncthreads();
    const char* ldsb = ldsc + b * BUF;
#pragma unroll
    for (int ks = 0; ks < 2; ++ks){
      bf8_t aH[2], aL[2], bH[2], bL[2];
#pragma unroll
      for (int f = 0; f < 2; ++f){
        int ar = wm * 32 + f * 16 + l15;
        int aoff = ar * 128 + (((ks * 64) + (l4 << 4)) ^ ((ar & 7) << 4));
        aH[f] = *(const bf8_t*)(ldsb + aoff);
        if (HAS_AL) aL[f] = *(const bf8_t*)(ldsb + 16384 + aoff);
        int br = wn * 32 + f * 16 + l15;
        int boff = br * 128 + (((ks * 64) + (l4 << 4)) ^ ((br & 7) << 4));
        bH[f] = *(const bf8_t*)(ldsb + 8192 + boff);
        if (HAS_BL) bL[f] = *(const bf8_t*)(ldsb + (2 + HAS_AL) * 8192 + boff);
      }
#pragma unroll
      for (int i = 0; i < 2; ++i)
#pragma unroll
        for (int j = 0; j < 2; ++j){
          acc[i][j] = __builtin_amdgcn_mfma_f32_16x16x32_bf16(aH[i], bH[j], acc[i][j], 0, 0, 0);
          if (HAS_BL) acc[i][j] = __builtin_amdgcn_mfma_f32_16x16x32_bf16(aH[i], bL[j], acc[i][j], 0, 0, 0);
          if (HAS_AL) acc[i][j] = __builtin_amdgcn_mfma_f32_16x16x32_bf16(aL[i], bH[j], acc[i][j], 0, 0, 0);
          if (HAS_LL) acc[i][j] = __builtin_amdgcn_mfma_f32_16x16x32_bf16(aL[i], bL[j], acc[i][j], 0, 0, 0);
        }
    }
    __syncthreads();
    b ^= 1;
  }

  float* Pz = (EPI == 0) ? P + (size_t)z * M * N : nullptr;
#pragma unroll
  for (int i = 0; i < 2; ++i)
#pragma unroll
    for (int j = 0; j < 2; ++j)
#pragma unroll
      for (int r = 0; r < 4; ++r){
        int grow = bm + wm * 32 + i * 16 + l4 * 4 + r;
        int gcol = bn + wn * 32 + j * 16 + l15;
        float v = acc[i][j][r];
        size_t o = (size_t)grow * N + gcol;
        if (EPI == 0){
          Pz[o] = v;
        } else if (EPI == 2){
          Cf[o] = dinv[grow] * v;
        } else { // EPI == 4
          float sv = dinv[grow] * v;
          Cf[o] = sv;
          unsigned short h = f2bf(sv);
          size_t ot = (size_t)gcol * M + grow;
          Ch[ot] = h; Cl[ot] = f2bf(sv - bf2f(h));
        }
      }
}

// ---------------- split-K reduce, wave-per-row, float4 (4 rows per block) ----------------
// EPI 2: Of = relu?(dinv[row]*(s+2Zs)+bias); optional score (SC, NC==256)
// EPI 3: v = (c==row)?0:s; Oh/Ol = split(v); dout[row] = 1/sqrt(rowsum+2)
// EPI 4: out = relu?(dinv[row]*(s+2Zs)+bias); comb = res[perm[row]]+out; Oh/Ol[perm[row]*NC+c] = split(comb)
template<int EPI, int SC, int Z>
__global__ __launch_bounds__(256) void k_red(
    const float* __restrict__ P, int M, int NC,
    const float* __restrict__ dinv, const float* __restrict__ Zs,
    const float* __restrict__ bias,
    float* __restrict__ Of, unsigned short* __restrict__ Oh, unsigned short* __restrict__ Ol,
    float* __restrict__ dout, int relu,
    const float* __restrict__ scw, float* __restrict__ score,
    const float* __restrict__ res, const int* __restrict__ permsel)
{
  int w = threadIdx.x >> 6, lane = threadIdx.x & 63;
  int row = blockIdx.x * 4 + w;
  int prow = (EPI == 4) ? permsel[row] : 0;
  float di = (EPI != 3) ? dinv[row] : 0.f;
  float rsum = 0.f, o_d = 0.f, o_q = 0.f;
  for (int c0 = lane * 4; c0 < NC; c0 += 256){
    size_t o = (size_t)row * NC + c0;
    f4_t s = *(const f4_t*)(P + o);
#pragma unroll
    for (int zz = 1; zz < Z; ++zz) s += *(const f4_t*)(P + (size_t)zz * M * NC + o);
    if (EPI == 2){
      f4_t z4 = *(const f4_t*)(Zs + o);
      f4_t b4 = *(const f4_t*)(bias + c0);
      f4_t out;
#pragma unroll
      for (int j = 0; j < 4; ++j){
        float v = di * (s[j] + 2.0f * z4[j]) + b4[j];
        if (relu) v = fmaxf(v, 0.f);
        out[j] = v;
      }
      *(f4_t*)(Of + o) = out;
      if (SC){
        f4_t w4 = *(const f4_t*)(scw + c0);
#pragma unroll
        for (int j = 0; j < 4; ++j){ o_d += out[j] * w4[j]; o_q += w4[j] * w4[j]; }
      }
    } else if (EPI == 3){
      us4_t h4, l4v;
#pragma unroll
      for (int j = 0; j < 4; ++j){
        float v = (c0 + j == row) ? 0.f : s[j];
        unsigned short h = f2bf(v);
        h4[j] = h; l4v[j] = f2bf(v - bf2f(h));
        rsum += v;
      }
      *(us4_t*)(Oh + o) = h4;
      *(us4_t*)(Ol + o) = l4v;
    } else { // EPI == 4
      f4_t z4 = *(const f4_t*)(Zs + o);
      f4_t b4 = *(const f4_t*)(bias + c0);
      f4_t r4 = *(const f4_t*)(res + (size_t)prow * NC + c0);
      us4_t h4, l4v;
#pragma unroll
      for (int j = 0; j < 4; ++j){
        float v = di * (s[j] + 2.0f * z4[j]) + b4[j];
        if (relu) v = fmaxf(v, 0.f);
        float comb = r4[j] + v;
        unsigned short h = f2bf(comb);
        h4[j] = h; l4v[j] = f2bf(comb - bf2f(h));
      }
      size_t od = (size_t)prow * NC + c0;
      *(us4_t*)(Oh + od) = h4;
      *(us4_t*)(Ol + od) = l4v;
    }
  }
  if (EPI == 3){
    rsum = waveReduceSum(rsum);
    if (!lane) dout[row] = 1.0f / sqrtf(rsum + 2.0f);
  }
  if (SC){
    o_d = waveReduceSum(o_d);
    o_q = waveReduceSum(o_q);
    if (!lane) score[row] = tanhf(o_d / sqrtf(o_q));
  }
}

// ---------------- topk (stable descending rank) ----------------
__global__ void k_topk(const float* __restrict__ score, int n, int k,
                       int* __restrict__ perm, int* __restrict__ inv){
  int i = blockIdx.x; float si = score[i];
  int cnt = 0;
  for (int j = threadIdx.x; j < n; j += 256){
    float sj = score[j];
    if (sj > si || (sj == si && j < i)) cnt++;
  }
#pragma unroll
  for (int off = 32; off > 0; off >>= 1) cnt += __shfl_down(cnt, off);
  __shared__ int sh[4];
  int lane = threadIdx.x & 63, wid = threadIdx.x >> 6;
  if (lane == 0) sh[wid] = cnt;
  __syncthreads();
  if (threadIdx.x == 0){
    int rank = sh[0] + sh[1] + sh[2] + sh[3];
    if (rank < k){ perm[rank] = i; inv[i] = rank; }
    else inv[i] = -1;
  }
}

// ---------------- host orchestration ----------------
extern "C" void kernel_launch(void* const* d_in, const int* in_sizes, int n_in,
                              void* d_out, int out_size, void* d_ws, size_t ws_size,
                              hipStream_t stream){
  (void)in_sizes; (void)n_in; (void)out_size;
  const float* x_in = (const float*)d_in[0];
  const int*   ei   = (const int*)d_in[1];
  const float* dW0 = (const float*)d_in[2];
  const float* dW1 = (const float*)d_in[3];
  const float* dW2 = (const float*)d_in[4];
  const float* dW3 = (const float*)d_in[5];
  const float* db0 = (const float*)d_in[6];
  const float* db1 = (const float*)d_in[7];
  const float* db2 = (const float*)d_in[8];
  const float* db3 = (const float*)d_in[9];
  const float* pw0 = (const float*)d_in[10];
  const float* pw1 = (const float*)d_in[11];
  const float* pw2 = (const float*)d_in[12];
  const float* uW0 = (const float*)d_in[13];
  const float* uW1 = (const float*)d_in[14];
  const float* uW2 = (const float*)d_in[15];
  const float* ub0 = (const float*)d_in[16];
  const float* ub1 = (const float*)d_in[17];
  const float* ub2 = (const float*)d_in[18];

  char* p = (char*)d_ws;
  auto alloc = [&](size_t nbytes) -> void* {
    void* q = (void*)p; p += (nbytes + 255) & ~(size_t)255; return q;
  };
  unsigned* bits = (unsigned*)alloc((size_t)4096 * 128 * 4);
  int* ell = (int*)alloc((size_t)4096 * ECAP * 4);
  int* cnt = (int*)alloc(4096 * 4);
  int* inv1 = (int*)alloc(4096 * 4);
  int* inv2 = (int*)alloc(2048 * 4);
  int* inv3 = (int*)alloc(1024 * 4);
  unsigned short* Rb2 = (unsigned short*)alloc((size_t)4096 * 256 * 2);  // 2-bit packed
  float* Pp = (float*)alloc((size_t)8 * 1024 * 1024);   // split-K partials
  unsigned short* A1h = (unsigned short*)alloc((size_t)2048 * 2048 * 2);
  unsigned short* A2h = (unsigned short*)alloc((size_t)1024 * 1024 * 2);
  unsigned short* A2l = (unsigned short*)alloc((size_t)1024 * 1024 * 2);
  unsigned short* A3h = (unsigned short*)alloc((size_t)512 * 512 * 2);
  unsigned short* A3l = (unsigned short*)alloc((size_t)512 * 512 * 2);
  unsigned short* Lb2h = (unsigned short*)alloc((size_t)1024 * 2048 * 2);
  unsigned short* Rt2h = (unsigned short*)alloc((size_t)1024 * 2048 * 2);
  unsigned short* Lb3h = (unsigned short*)alloc((size_t)512 * 1024 * 2);
  unsigned short* Lb3l = (unsigned short*)alloc((size_t)512 * 1024 * 2);
  unsigned short* Rt3h = (unsigned short*)alloc((size_t)512 * 1024 * 2);
  unsigned short* Rt3l = (unsigned short*)alloc((size_t)512 * 1024 * 2);
  unsigned short* xinh = (unsigned short*)alloc((size_t)4096 * 512 * 2);
  unsigned short* xinl = (unsigned short*)alloc((size_t)4096 * 512 * 2);
  float* x0 = (float*)alloc((size_t)4096 * HID * 4);
  float* x1 = (float*)alloc((size_t)2048 * HID * 4);
  float* x2 = (float*)alloc((size_t)1024 * HID * 4);
  unsigned short* xu1h = (unsigned short*)alloc((size_t)4096 * HID * 2);
  unsigned short* xu1l = (unsigned short*)alloc((size_t)4096 * HID * 2);
  unsigned short* xu2h = (unsigned short*)alloc((size_t)2048 * HID * 2);
  unsigned short* xu2l = (unsigned short*)alloc((size_t)2048 * HID * 2);
  unsigned short* xu3h = (unsigned short*)alloc((size_t)1024 * HID * 2);
  unsigned short* xu3l = (unsigned short*)alloc((size_t)1024 * HID * 2);
  unsigned short* xph = (unsigned short*)alloc((size_t)2048 * HID * 2);
  unsigned short* xpl = (unsigned short*)alloc((size_t)2048 * HID * 2);
  unsigned short* W0th = (unsigned short*)alloc((size_t)256 * 512 * 2);
  unsigned short* W0tl = (unsigned short*)alloc((size_t)256 * 512 * 2);
  unsigned short* W5th = (unsigned short*)alloc((size_t)5 * 256 * 256 * 2);
  unsigned short* W5tl = (unsigned short*)alloc((size_t)5 * 256 * 256 * 2);
  unsigned short* W2th = (unsigned short*)alloc((size_t)64 * 256 * 2);
  unsigned short* W2tl = (unsigned short*)alloc((size_t)64 * 256 * 2);
  float* Zs  = (float*)alloc((size_t)4096 * HID * 4);
  unsigned short* ZsTh = (unsigned short*)alloc((size_t)256 * 2048 * 2);
  unsigned short* ZsTl = (unsigned short*)alloc((size_t)256 * 2048 * 2);
  float* dinv0 = (float*)alloc(4096 * 4);
  float* dinv1 = (float*)alloc(2048 * 4);
  float* dinv2 = (float*)alloc(1024 * 4);
  float* dinv3 = (float*)alloc(512 * 4);
  float* score = (float*)alloc(4096 * 4);
  int* perm1 = (int*)alloc(2048 * 4);
  int* perm2 = (int*)alloc(1024 * 4);
  int* perm3 = (int*)alloc(512 * 4);
  if ((size_t)(p - (char*)d_ws) > ws_size) return;

  // 1: prep (bits zero + x split + all weight tsplits)
  k_prep<<<2640, 256, 0, stream>>>(x_in, dW0, dW1, dW2, dW3, uW0, uW1, uW2, bits,
                                   xinh, xinl, W0th, W0tl, W5th, W5tl, W2th, W2tl);
  // 2-3: graph build
  k_build_bits<<<EE / 256, 256, 0, stream>>>(ei, bits);
  k_ell<<<4096, 128, 0, stream>>>(bits, ell, cnt, dinv0);

  // 4-5: conv0 (+ pool-1 score fused)
  { dim3 g(4, 64);
    k_mm<1,1,0,2><<<g, 256, 0, stream>>>(xinh, xinl, W0th, W0tl, 4096, HID, IN_DIM, IN_DIM,
                                         nullptr, Zs, nullptr, nullptr, dinv0); }
  k_spmm_ell<256,1,1><<<4096, 256, 0, stream>>>(ell, cnt, Zs, dinv0, db0, x0, pw0, score);

  // 6-8: pool 1 (4096 -> 2048)
  k_topk<<<4096, 256, 0, stream>>>(score, 4096, 2048, perm1, inv1);
  k_pool_build<<<10240, 256, 0, stream>>>(x0, score, perm1, inv1, ell, cnt,
                                          xph, xpl, Rb2, xu1h, xu1l);
  k_sq1<<<2048, 256, 0, stream>>>(ell, cnt, perm1, Rb2, A1h, dinv1);
  // 9-11: conv1 (g1 EPI4; g2 split-K z=4; red -> x1 + score2)
  { dim3 g(4, 32);
    k_mm<1,1,0,4><<<g, 256, 0, stream>>>(xph, xpl, W5th, W5tl, 2048, HID, HID, HID,
                                         nullptr, Zs, ZsTh, ZsTl, dinv1); }
  { dim3 g(4, 32, 4);
    k_mm<0,1,0,0><<<g, 256, 0, stream>>>(A1h, nullptr, ZsTh, ZsTl, 2048, HID, 2048, 512,
                                         Pp, nullptr, nullptr, nullptr, nullptr); }
  k_red<2,1,4><<<512, 256, 0, stream>>>(Pp, 2048, 256, dinv1, Zs, db1,
                                        x1, nullptr, nullptr, nullptr, 1, pw1, score, nullptr, nullptr);

  // 12-15: pool 2 (2048 -> 1024)
  k_topk<<<2048, 256, 0, stream>>>(score, 2048, 1024, perm2, inv2);
  k_pp<0,0><<<8192, 256, 0, stream>>>(x1, score, perm2, inv2, 2048, 1024,
                                      xph, xpl, xu2h, xu2l, A1h, nullptr,
                                      Lb2h, nullptr, Rt2h, nullptr);
  { dim3 g(16, 16, 2);
    k_mm<0,0,0,0><<<g, 256, 0, stream>>>(Lb2h, nullptr, Rt2h, nullptr, 1024, 1024, 2048, 1024,
                                         Pp, nullptr, nullptr, nullptr, nullptr); }
  k_red<3,0,2><<<256, 256, 0, stream>>>(Pp, 1024, 1024, nullptr, nullptr, nullptr,
                                        nullptr, A2h, A2l, dinv2, 0, nullptr, nullptr, nullptr, nullptr);
  // 16-18: conv2
  { dim3 g(4, 16);
    k_mm<1,1,0,4><<<g, 256, 0, stream>>>(xph, xpl, W5th + 65536, W5tl + 65536, 1024, HID, HID, HID,
                                         nullptr, Zs, ZsTh, ZsTl, dinv2); }
  { dim3 g(4, 16, 4);
    k_mm<1,1,0,0><<<g, 256, 0, stream>>>(A2h, A2l, ZsTh, ZsTl, 1024, HID, 1024, 256,
                                         Pp, nullptr, nullptr, nullptr, nullptr); }
  k_red<2,1,4><<<256, 256, 0, stream>>>(Pp, 1024, 256, dinv2, Zs, db2,
                                        x2, nullptr, nullptr, nullptr, 1, pw2, score, nullptr, nullptr);

  // 19-22: pool 3 (1024 -> 512)
  k_topk<<<1024, 256, 0, stream>>>(score, 1024, 512, perm3, inv3);
  k_pp<1,1><<<3072, 256, 0, stream>>>(x2, score, perm3, inv3, 1024, 512,
                                      xph, xpl, xu3h, xu3l, A2h, A2l,
                                      Lb3h, Lb3l, Rt3h, Rt3l);
  { dim3 g(8, 8, 4);
    k_mm<1,1,1,0><<<g, 256, 0, stream>>>(Lb3h, Lb3l, Rt3h, Rt3l, 512, 512, 1024, 256,
                                         Pp, nullptr, nullptr, nullptr, nullptr); }
  k_red<3,0,4><<<128, 256, 0, stream>>>(Pp, 512, 512, nullptr, nullptr, nullptr,
                                        nullptr, A3h, A3l, dinv3, 0, nullptr, nullptr, nullptr, nullptr);
  // 23-25: conv3 -> scatter into xu3
  { dim3 g(4, 8);
    k_mm<1,1,0,4><<<g, 256, 0, stream>>>(xph, xpl, W5th + 2 * 65536, W5tl + 2 * 65536, 512, HID, HID, HID,
                                         nullptr, Zs, ZsTh, ZsTl, dinv3); }
  { dim3 g(4, 8, 4);
    k_mm<1,1,0,0><<<g, 256, 0, stream>>>(A3h, A3l, ZsTh, ZsTl, 512, HID, 512, 128,
                                         Pp, nullptr, nullptr, nullptr, nullptr); }
  k_red<4,0,4><<<128, 256, 0, stream>>>(Pp, 512, 256, dinv3, Zs, db3,
                                        nullptr, xu3h, xu3l, nullptr, 1, nullptr, nullptr, x2, perm3);

  // 26-28: up0 -> scatter into xu2
  { dim3 g(4, 16);
    k_mm<1,1,0,4><<<g, 256, 0, stream>>>(xu3h, xu3l, W5th + 3 * 65536, W5tl + 3 * 65536, 1024, HID, HID, HID,
                                         nullptr, Zs, ZsTh, ZsTl, dinv2); }
  { dim3 g(4, 16, 4);
    k_mm<1,1,0,0><<<g, 256, 0, stream>>>(A2h, A2l, ZsTh, ZsTl, 1024, HID, 1024, 256,
                                         Pp, nullptr, nullptr, nullptr, nullptr); }
  k_red<4,0,4><<<256, 256, 0, stream>>>(Pp, 1024, 256, dinv2, Zs, ub0,
                                        nullptr, xu2h, xu2l, nullptr, 1, nullptr, nullptr, x1, perm2);

  // 29-31: up1 -> scatter into xu1
  { dim3 g(4, 32);
    k_mm<1,1,0,4><<<g, 256, 0, stream>>>(xu2h, xu2l, W5th + 4 * 65536, W5tl + 4 * 65536, 2048, HID, HID, HID,
                                         nullptr, Zs, ZsTh, ZsTl, dinv1); }
  { dim3 g(4, 32, 4);
    k_mm<0,1,0,0><<<g, 256, 0, stream>>>(A1h, nullptr, ZsTh, ZsTl, 2048, HID, 2048, 512,
                                         Pp, nullptr, nullptr, nullptr, nullptr); }
  k_red<4,0,4><<<512, 256, 0, stream>>>(Pp, 2048, 256, dinv1, Zs, ub1,
                                        nullptr, xu1h, xu1l, nullptr, 1, nullptr, nullptr, x0, perm1);

  // 32-33: up2 (A0 sparse, Cout=64, no relu)
  { dim3 g(1, 64);
    k_mm<1,1,0,2><<<g, 256, 0, stream>>>(xu1h, xu1l, W2th, W2tl, 4096, OUT_DIM, HID, HID,
                                         nullptr, Zs, nullptr, nullptr, dinv0); }
  k_spmm_ell<64,0,0><<<4096, 256, 0, stream>>>(ell, cnt, Zs, dinv0, ub2, (float*)d_out, nullptr, nullptr);
}

// Round 11
// 224.867 us; speedup vs baseline: 1.0724x; 1.0148x over previous
//
#include <hip/hip_runtime.h>
#include <math.h>

#define NN 4096
#define EE 131072
#define IN_DIM 512
#define HID 256
#define OUT_DIM 64
#define ECAP 128

typedef __attribute__((ext_vector_type(8))) short bf8_t;
typedef __attribute__((ext_vector_type(4))) float f4_t;
typedef __attribute__((ext_vector_type(8))) unsigned short us8_t;
typedef __attribute__((ext_vector_type(4))) unsigned short us4_t;

#define GAS __attribute__((address_space(1)))
#define LAS __attribute__((address_space(3)))

// ---------------- bf16 helpers (RNE) ----------------
__device__ __forceinline__ unsigned short f2bf(float v){
  union { float f; unsigned u; } x; x.f = v;
  unsigned r = x.u + 0x7fffu + ((x.u >> 16) & 1u);
  return (unsigned short)(r >> 16);
}
__device__ __forceinline__ float bf2f(unsigned short h){
  union { float f; unsigned u; } x; x.u = ((unsigned)h) << 16;
  return x.f;
}

__device__ __forceinline__ float waveReduceSum(float v){
#pragma unroll
  for (int off = 32; off > 0; off >>= 1) v += __shfl_down(v, off);
  return v;
}

// ---------------- mega-prep: zero bits + split x_in + transpose-split all weights ----------------
__global__ __launch_bounds__(256) void k_prep(
    const float* __restrict__ x_in, const float* __restrict__ dW0,
    const float* __restrict__ dW1, const float* __restrict__ dW2,
    const float* __restrict__ dW3, const float* __restrict__ uW0,
    const float* __restrict__ uW1, const float* __restrict__ uW2,
    unsigned* __restrict__ bits,
    unsigned short* __restrict__ xinh, unsigned short* __restrict__ xinl,
    unsigned short* __restrict__ W0th, unsigned short* __restrict__ W0tl,
    unsigned short* __restrict__ W5th, unsigned short* __restrict__ W5tl,
    unsigned short* __restrict__ W2th, unsigned short* __restrict__ W2tl)
{
  int b = blockIdx.x;
  if (b < 128){                       // zero 2MB bit-adjacency
    int base = b * 4096 + threadIdx.x;
#pragma unroll
    for (int i = 0; i < 16; ++i) bits[base + i * 256] = 0;
    return;
  }
  b -= 128;
  if (b < 2048){                      // split x_in (4096x512 fp32 -> bf16 hi/lo)
    int i0 = b * 1024 + threadIdx.x;
#pragma unroll
    for (int i = 0; i < 4; ++i){
      int idx = i0 + i * 256;
      float v = x_in[idx];
      unsigned short h = f2bf(v);
      xinh[idx] = h; xinl[idx] = f2bf(v - bf2f(h));
    }
    return;
  }
  b -= 2048;
  const float* X; unsigned short *Th, *Tl; int R, C, tile;
  if (b < 128){ X = dW0; Th = W0th; Tl = W0tl; R = 512; C = 256; tile = b; }
  else if (b < 448){
    int t2 = b - 128; int z = t2 >> 6; int rem = t2 & 63;
    const float* ws[5] = {dW1, dW2, dW3, uW0, uW1};
    X = ws[z]; Th = W5th + (size_t)z * 65536; Tl = W5tl + (size_t)z * 65536;
    R = 256; C = 256; tile = rem;
  } else { X = uW2; Th = W2th; Tl = W2tl; R = 256; C = 64; tile = b - 448; }
  int tpr = C >> 5;
  int bx = (tile % tpr) * 32, by = (tile / tpr) * 32;
  __shared__ float t[32][33];
  int tx = threadIdx.x & 31, ty = threadIdx.x >> 5;
#pragma unroll
  for (int i = 0; i < 4; ++i)
    t[ty + i * 8][tx] = X[(size_t)(by + ty + i * 8) * C + bx + tx];
  __syncthreads();
#pragma unroll
  for (int i = 0; i < 4; ++i){
    float v = t[tx][ty + i * 8];
    unsigned short h = f2bf(v);
    size_t o = (size_t)(bx + ty + i * 8) * R + by + tx;
    Th[o] = h; Tl[o] = f2bf(v - bf2f(h));
  }
}

// ---------------- graph build: bitmask + ELL ----------------
__global__ void k_build_bits(const int* __restrict__ ei, unsigned* __restrict__ bits){
  int e = blockIdx.x * blockDim.x + threadIdx.x;
  if (e < EE){
    int r = ei[e], c = ei[EE + e];
    atomicOr(&bits[r * 128 + (c >> 5)], 1u << (c & 31));
  }
}

__global__ __launch_bounds__(128) void k_ell(const unsigned* __restrict__ bits,
                                             int* __restrict__ ell, int* __restrict__ cnt,
                                             float* __restrict__ dinv){
  int r = blockIdx.x, t = threadIdx.x;
  unsigned w = bits[r * 128 + t];
  int c = __popc(w);
  __shared__ int sc[128];
  sc[t] = c; __syncthreads();
  for (int off = 1; off < 128; off <<= 1){
    int a = sc[t], b = (t >= off) ? sc[t - off] : 0;
    __syncthreads(); sc[t] = a + b; __syncthreads();
  }
  int total = sc[127];
  int pos = sc[t] - c;
  int base = r * ECAP;
  while (w){
    int b = __ffs(w) - 1; w &= w - 1;
    if (pos < ECAP) ell[base + pos] = t * 32 + b;
    pos++;
  }
  if (t == 0){
    cnt[r] = (total < ECAP) ? total : ECAP;
    dinv[r] = 1.0f / sqrtf((float)total + 2.0f);
  }
}

// ---------------- fused SpMM (ELL, values==1) + GCN epilogue (+ optional score) ----------------
template<int NCOLS, int RELU, int SC>
__global__ __launch_bounds__(256) void k_spmm_ell(
    const int* __restrict__ ell, const int* __restrict__ cnt,
    const float* __restrict__ Zs, const float* __restrict__ dinv,
    const float* __restrict__ bias, float* __restrict__ out,
    const float* __restrict__ scw, float* __restrict__ score)
{
  int r = blockIdx.x;
  __shared__ int s_idx[ECAP];
  __shared__ int s_n;
  __shared__ float sh[4 * NCOLS];
  __shared__ float sd[4], sq[4];
  if (threadIdx.x == 0) s_n = cnt[r];
  __syncthreads();
  int n = s_n; if (n > ECAP) n = ECAP;
  for (int i = threadIdx.x; i < n; i += 256) s_idx[i] = ell[r * ECAP + i];
  __syncthreads();
  int wv = threadIdx.x >> 6, lane = threadIdx.x & 63;
  if (NCOLS == 256){
    f4_t acc = (f4_t){0.f, 0.f, 0.f, 0.f};
    for (int e = wv; e < n; e += 4){
      const f4_t* row = (const f4_t*)(Zs + (size_t)s_idx[e] * 256);
      acc += row[lane];
    }
    ((f4_t*)(sh + wv * 256))[lane] = acc;
  } else {
    float acc = 0.f;
    for (int e = wv; e < n; e += 4)
      acc += Zs[(size_t)s_idx[e] * 64 + lane];
    sh[wv * 64 + lane] = acc;
  }
  __syncthreads();
  int t = threadIdx.x;
  float o = 0.f;
  if (t < NCOLS){
    float y = sh[t] + sh[NCOLS + t] + sh[2 * NCOLS + t] + sh[3 * NCOLS + t];
    float z = Zs[(size_t)r * NCOLS + t];
    o = dinv[r] * (y + 2.0f * z) + bias[t];
    if (RELU) o = fmaxf(o, 0.f);
    out[(size_t)r * NCOLS + t] = o;
  }
  if (SC){
    float w = scw[t];
    float d = waveReduceSum(o * w);
    float q = waveReduceSum(w * w);
    if (!lane){ sd[wv] = d; sq[wv] = q; }
    __syncthreads();
    if (!t) score[r] = tanhf((sd[0] + sd[1] + sd[2] + sd[3]) / sqrtf(sq[0] + sq[1] + sq[2] + sq[3]));
  }
}

// ---------------- pool1: pool_x2 + build_Rb (2-bit packed) + xu1 fill ----------------
__global__ __launch_bounds__(256) void k_pool_build(
    const float* __restrict__ x0, const float* __restrict__ score,
    const int* __restrict__ perm1, const int* __restrict__ inv1,
    const int* __restrict__ ell, const int* __restrict__ cnt,
    unsigned short* __restrict__ xph, unsigned short* __restrict__ xpl,
    unsigned short* __restrict__ Rb2,
    unsigned short* __restrict__ xu1h, unsigned short* __restrict__ xu1l)
{
  int b = blockIdx.x;
  if (b < 2048){                           // gated pooled features
    int pr = perm1[b]; float s = score[pr];
    int c = threadIdx.x;
    float v = x0[(size_t)pr * 256 + c] * s;
    unsigned short h = f2bf(v);
    xph[(size_t)b * 256 + c] = h;
    xpl[(size_t)b * 256 + c] = f2bf(v - bf2f(h));
    return;
  }
  if (b < 6144){                           // Rb2[k]: 2-bit packed (A0+I)[k][perm1[s]]
    int k = b - 2048;
    __shared__ unsigned char row[2048];
    for (int i = threadIdx.x; i < 512; i += 256) ((int*)row)[i] = 0;
    __syncthreads();
    int n = cnt[k];
    for (int e = threadIdx.x; e < n; e += 256){
      int s = inv1[ell[k * ECAP + e]];
      if (s >= 0) row[s] = 1;
    }
    __syncthreads();
    if (threadIdx.x == 0){
      int sk = inv1[k];
      if (sk >= 0) row[sk] += 1;
    }
    __syncthreads();
    unsigned w = 0;
#pragma unroll
    for (int j = 0; j < 8; ++j) w |= ((unsigned)row[(threadIdx.x << 3) + j]) << (2 * j);
    Rb2[k * 256 + threadIdx.x] = (unsigned short)w;
    return;
  }
  int r = b - 6144;                        // xu1 fill: non-selected rows = x0
  if (inv1[r] < 0){
    int c = threadIdx.x;
    float v = x0[(size_t)r * 256 + c];
    unsigned short h = f2bf(v);
    xu1h[(size_t)r * 256 + c] = h;
    xu1l[(size_t)r * 256 + c] = f2bf(v - bf2f(h));
  }
}

// ---------------- pool2/3 prep: pooled-x + xu fill + L row-gather(+I) + transpose-gather(+I) ----------------
template<int SRCL, int OUTL>
__global__ __launch_bounds__(256) void k_pp(
    const float* __restrict__ x, const float* __restrict__ score,
    const int* __restrict__ perm, const int* __restrict__ inv, int n, int k,
    unsigned short* __restrict__ xph, unsigned short* __restrict__ xpl,
    unsigned short* __restrict__ xuh, unsigned short* __restrict__ xul,
    const unsigned short* __restrict__ Ah, const unsigned short* __restrict__ Al,
    unsigned short* __restrict__ Lh, unsigned short* __restrict__ Ll,
    unsigned short* __restrict__ Rh, unsigned short* __restrict__ Rl)
{
  __shared__ float t[32][33];
  __shared__ int sinv[32];
  int b = blockIdx.x, c = threadIdx.x;
  if (b < k){
    int pr = perm[b]; float s = score[pr];
    float v = x[(size_t)pr * 256 + c] * s;
    unsigned short h = f2bf(v);
    xph[(size_t)b * 256 + c] = h;
    xpl[(size_t)b * 256 + c] = f2bf(v - bf2f(h));
    return;
  }
  b -= k;
  if (b < n){
    if (inv[b] < 0){
      float v = x[(size_t)b * 256 + c];
      unsigned short h = f2bf(v);
      xuh[(size_t)b * 256 + c] = h;
      xul[(size_t)b * 256 + c] = f2bf(v - bf2f(h));
    }
    return;
  }
  b -= n;
  if (b < k){
    int r = b, pr = perm[r];
    for (int cc = threadIdx.x; cc < n; cc += 256){
      float v = bf2f(Ah[(size_t)pr * n + cc]);
      if (SRCL) v += bf2f(Al[(size_t)pr * n + cc]);
      if (pr == cc) v += 1.f;
      unsigned short h = f2bf(v);
      Lh[(size_t)r * n + cc] = h;
      if (OUTL) Ll[(size_t)r * n + cc] = f2bf(v - bf2f(h));
    }
    return;
  }
  b -= k;
  int tpr = n >> 5;
  int kt = b / tpr, ct = b - kt * tpr;
  int tx = threadIdx.x & 31, ty = threadIdx.x >> 5;
  if (threadIdx.x < 32) sinv[threadIdx.x] = inv[ct * 32 + threadIdx.x];
#pragma unroll
  for (int i = 0; i < 4; ++i){
    int kl = ty + i * 8;
    size_t src = (size_t)(kt * 32 + kl) * n + ct * 32 + tx;
    float v = bf2f(Ah[src]);
    if (SRCL) v += bf2f(Al[src]);
    t[kl][tx] = v;
  }
  __syncthreads();
#pragma unroll
  for (int i = 0; i < 4; ++i){
    int cl = ty + i * 8;
    int s = sinv[cl];
    if (s >= 0){
      float v = t[tx][cl];
      if (kt * 32 + tx == ct * 32 + cl) v += 1.f;
      unsigned short h = f2bf(v);
      size_t o = (size_t)s * n + kt * 32 + tx;
      Rh[o] = h;
      if (OUTL) Rl[o] = f2bf(v - bf2f(h));
    }
  }
}

// ---------------- pool-1 squaring from ELL (2-bit packed Rb) ----------------
__global__ __launch_bounds__(256) void k_sq1(const int* __restrict__ ell, const int* __restrict__ cnt,
                                             const int* __restrict__ perm,
                                             const unsigned short* __restrict__ Rb2,
                                             unsigned short* __restrict__ A1h,
                                             float* __restrict__ dinv1){
  int r = blockIdx.x;
  int pr = perm[r];
  __shared__ int s_idx[ECAP];
  __shared__ int s_n;
  __shared__ float sred[4];
  if (threadIdx.x == 0) s_n = cnt[pr];
  for (int i = threadIdx.x; i < ECAP; i += 256) s_idx[i] = ell[pr * ECAP + i];
  __syncthreads();
  int n = s_n; if (n > ECAP) n = ECAP;
  int colb = threadIdx.x * 8;
  auto expand = [](unsigned x) -> uint2 {
    uint2 e;
    e.x = (x & 3) | (((x >> 2) & 3) << 8) | (((x >> 4) & 3) << 16) | (((x >> 6) & 3) << 24);
    e.y = ((x >> 8) & 3) | (((x >> 10) & 3) << 8) | (((x >> 12) & 3) << 16) | (((x >> 14) & 3) << 24);
    return e;
  };
  uint2 acc = expand(Rb2[pr * 256 + threadIdx.x]);
  for (int e = 0; e < n; ++e){
    uint2 v = expand(Rb2[s_idx[e] * 256 + threadIdx.x]);
    acc.x += v.x; acc.y += v.y;   // bytewise, no carries (values <=130)
  }
  float fs = 0.f;
  us8_t o;
#pragma unroll
  for (int j = 0; j < 8; ++j){
    unsigned byte = ((j < 4 ? acc.x : acc.y) >> (8 * (j & 3))) & 0xFFu;
    if (colb + j == r) byte = 0;
    float f = (float)byte;
    fs += f;
    o[j] = f2bf(f);
  }
  *(us8_t*)(A1h + (size_t)r * 2048 + colb) = o;
  fs = waveReduceSum(fs);
  int lane = threadIdx.x & 63, wd = threadIdx.x >> 6;
  if (!lane) sred[wd] = fs;
  __syncthreads();
  if (!threadIdx.x)
    dinv1[r] = 1.0f / sqrtf(sred[0] + sred[1] + sred[2] + sred[3] + 2.0f);
}

// ---------------- MFMA GEMM: global_load_lds dbuf + XCD-swizzled blocks ----------------
// EPI 0: write fp32 partial P[z][M][N] (split-K)
// EPI 2: Cf = dinv[row]*acc
// EPI 4: sv = dinv[row]*acc; Cf = sv; Ch/Cl[col*M+row] = split(sv) via LDS transpose (coalesced)
template<int HAS_AL, int HAS_BL, int HAS_LL, int EPI>
__global__ __launch_bounds__(256) void k_mm(
    const unsigned short* __restrict__ Ah, const unsigned short* __restrict__ Al,
    const unsigned short* __restrict__ Bh, const unsigned short* __restrict__ Bl,
    int M, int N, int K, int KS, float* __restrict__ P,
    float* __restrict__ Cf, unsigned short* __restrict__ Ch, unsigned short* __restrict__ Cl,
    const float* __restrict__ dinv)
{
  constexpr int NARR = 2 + HAS_AL + HAS_BL;
  constexpr int BUF = NARR * 8192;
  __shared__ int4 ldsq[NARR * 512 * 2];
  char* ldsc = (char*)ldsq;

  const int tid = threadIdx.x, lane = tid & 63, wid = tid >> 6;
  const int wm = wid >> 1, wn = wid & 1;
  // XCD-aware bijective swizzle (grid sizes are all multiples of 8)
  const int nbx = gridDim.x, nby = gridDim.y;
  const int tot = nbx * nby * gridDim.z;
  int id = blockIdx.x + nbx * (blockIdx.y + nby * blockIdx.z);
  if ((tot & 7) == 0) id = (id & 7) * (tot >> 3) + (id >> 3);
  const int sx = id % nbx; int remq = id / nbx;
  const int sy = remq % nby;
  const int bm = sy << 6, bn = sx << 6;
  const int z = remq / nby;
  const int l15 = lane & 15, l4 = lane >> 4;

  f4_t acc[2][2];
#pragma unroll
  for (int i = 0; i < 2; ++i)
#pragma unroll
    for (int j = 0; j < 2; ++j) acc[i][j] = (f4_t){0.f, 0.f, 0.f, 0.f};

  const size_t rb = (size_t)K * 2;
  const size_t kz = (size_t)z * KS * 2;
  const char* pAh = (const char*)Ah + (size_t)bm * rb;
  const char* pAl = HAS_AL ? (const char*)Al + (size_t)bm * rb : nullptr;
  const char* pBh = (const char*)Bh + (size_t)bn * rb;
  const char* pBl = HAS_BL ? (const char*)Bl + (size_t)bn * rb : nullptr;

  auto stage = [&](int t, int b2){
    char* ldsb = ldsc + b2 * BUF;
    const size_t kb = kz + (size_t)t * 128;
#pragma unroll
    for (int it = 0; it < 2; ++it){
      const int idx = tid + (it << 8);
      const int row = idx >> 3;
      const int kc = ((idx & 7) << 4) ^ ((row & 7) << 4);  // pre-swizzled source col
      const size_t go = (size_t)row * rb + kb + kc;
      const int lo = idx * 16;
      __builtin_amdgcn_global_load_lds((const GAS void*)(pAh + go), (LAS void*)(ldsb + lo), 16, 0, 0);
      __builtin_amdgcn_global_load_lds((const GAS void*)(pBh + go), (LAS void*)(ldsb + 8192 + lo), 16, 0, 0);
      if (HAS_AL)
        __builtin_amdgcn_global_load_lds((const GAS void*)(pAl + go), (LAS void*)(ldsb + 16384 + lo), 16, 0, 0);
      if (HAS_BL)
        __builtin_amdgcn_global_load_lds((const GAS void*)(pBl + go), (LAS void*)(ldsb + (2 + HAS_AL) * 8192 + lo), 16, 0, 0);
    }
  };

  const int T = KS >> 6;
  stage(0, 0);
  int b = 0;
  for (int t = 0; t < T; ++t){
    if (t + 1 < T){
      stage(t + 1, b ^ 1);
      if constexpr (NARR == 2) asm volatile("s_waitcnt vmcnt(4)" ::: "memory");
      else if constexpr (NARR == 3) asm volatile("s_waitcnt vmcnt(6)" ::: "memory");
      else asm volatile("s_waitcnt vmcnt(8)" ::: "memory");
    } else {
      asm volatile("s_waitcnt vmcnt(0)" ::: "memory");
    }
    __syncthreads();
    const char* ldsb = ldsc + b * BUF;
#pragma unroll
    for (int ks = 0; ks < 2; ++ks){
      bf8_t aH[2], aL[2], bH[2], bL[2];
#pragma unroll
      for (int f = 0; f < 2; ++f){
        int ar = wm * 32 + f * 16 + l15;
        int aoff = ar * 128 + (((ks * 64) + (l4 << 4)) ^ ((ar & 7) << 4));
        aH[f] = *(const bf8_t*)(ldsb + aoff);
        if (HAS_AL) aL[f] = *(const bf8_t*)(ldsb + 16384 + aoff);
        int br = wn * 32 + f * 16 + l15;
        int boff = br * 128 + (((ks * 64) + (l4 << 4)) ^ ((br & 7) << 4));
        bH[f] = *(const bf8_t*)(ldsb + 8192 + boff);
        if (HAS_BL) bL[f] = *(const bf8_t*)(ldsb + (2 + HAS_AL) * 8192 + boff);
      }
#pragma unroll
      for (int i = 0; i < 2; ++i)
#pragma unroll
        for (int j = 0; j < 2; ++j){
          acc[i][j] = __builtin_amdgcn_mfma_f32_16x16x32_bf16(aH[i], bH[j], acc[i][j], 0, 0, 0);
          if (HAS_BL) acc[i][j] = __builtin_amdgcn_mfma_f32_16x16x32_bf16(aH[i], bL[j], acc[i][j], 0, 0, 0);
          if (HAS_AL) acc[i][j] = __builtin_amdgcn_mfma_f32_16x16x32_bf16(aL[i], bH[j], acc[i][j], 0, 0, 0);
          if (HAS_LL) acc[i][j] = __builtin_amdgcn_mfma_f32_16x16x32_bf16(aL[i], bL[j], acc[i][j], 0, 0, 0);
        }
    }
    __syncthreads();
    b ^= 1;
  }

  if (EPI == 4){
    // store Cf row-major (coalesced) + stash scaled tile in LDS, then
    // write transposed split via coalesced us8 vector stores.
    float* LT = (float*)ldsc;   // [64][68] fp32 = 17.4 KB (LDS >= 32 KB)
#pragma unroll
    for (int i = 0; i < 2; ++i)
#pragma unroll
      for (int j = 0; j < 2; ++j)
#pragma unroll
        for (int r = 0; r < 4; ++r){
          int lr = wm * 32 + i * 16 + l4 * 4 + r;
          int lc = wn * 32 + j * 16 + l15;
          float sv = dinv[bm + lr] * acc[i][j][r];
          Cf[(size_t)(bm + lr) * N + bn + lc] = sv;
          LT[lr * 68 + lc] = sv;
        }
    __syncthreads();
    int col = tid >> 2;            // 0..63 (output row of ZsT)
    int seg = (tid & 3) << 4;      // 16 m-values per thread
    us8_t h0, h1, l0, l1;
#pragma unroll
    for (int mm = 0; mm < 8; ++mm){
      float v = LT[(seg + mm) * 68 + col];
      unsigned short h = f2bf(v);
      h0[mm] = h; l0[mm] = f2bf(v - bf2f(h));
    }
#pragma unroll
    for (int mm = 0; mm < 8; ++mm){
      float v = LT[(seg + 8 + mm) * 68 + col];
      unsigned short h = f2bf(v);
      h1[mm] = h; l1[mm] = f2bf(v - bf2f(h));
    }
    size_t ob = (size_t)(bn + col) * M + bm + seg;
    *(us8_t*)(Ch + ob) = h0;
    *(us8_t*)(Ch + ob + 8) = h1;
    *(us8_t*)(Cl + ob) = l0;
    *(us8_t*)(Cl + ob + 8) = l1;
    return;
  }

  float* Pz = (EPI == 0) ? P + (size_t)z * M * N : nullptr;
#pragma unroll
  for (int i = 0; i < 2; ++i)
#pragma unroll
    for (int j = 0; j < 2; ++j)
#pragma unroll
      for (int r = 0; r < 4; ++r){
        int grow = bm + wm * 32 + i * 16 + l4 * 4 + r;
        int gcol = bn + wn * 32 + j * 16 + l15;
        float v = acc[i][j][r];
        size_t o = (size_t)grow * N + gcol;
        if (EPI == 0){
          Pz[o] = v;
        } else { // EPI == 2
          Cf[o] = dinv[grow] * v;
        }
      }
}

// ---------------- split-K reduce, wave-per-row, float4 (4 rows per block) ----------------
// EPI 2: Of = relu?(dinv[row]*(s+2Zs)+bias); optional score (SC, NC==256)
// EPI 3: v = (c==row)?0:s; Oh/Ol = split(v); dout[row] = 1/sqrt(rowsum+2)
// EPI 4: out = relu?(dinv[row]*(s+2Zs)+bias); comb = res[perm[row]]+out; Oh/Ol[perm[row]*NC+c] = split(comb)
template<int EPI, int SC, int Z>
__global__ __launch_bounds__(256) void k_red(
    const float* __restrict__ P, int M, int NC,
    const float* __restrict__ dinv, const float* __restrict__ Zs,
    const float* __restrict__ bias,
    float* __restrict__ Of, unsigned short* __restrict__ Oh, unsigned short* __restrict__ Ol,
    float* __restrict__ dout, int relu,
    const float* __restrict__ scw, float* __restrict__ score,
    const float* __restrict__ res, const int* __restrict__ permsel)
{
  int w = threadIdx.x >> 6, lane = threadIdx.x & 63;
  int row = blockIdx.x * 4 + w;
  int prow = (EPI == 4) ? permsel[row] : 0;
  float di = (EPI != 3) ? dinv[row] : 0.f;
  float rsum = 0.f, o_d = 0.f, o_q = 0.f;
  for (int c0 = lane * 4; c0 < NC; c0 += 256){
    size_t o = (size_t)row * NC + c0;
    f4_t s = *(const f4_t*)(P + o);
#pragma unroll
    for (int zz = 1; zz < Z; ++zz) s += *(const f4_t*)(P + (size_t)zz * M * NC + o);
    if (EPI == 2){
      f4_t z4 = *(const f4_t*)(Zs + o);
      f4_t b4 = *(const f4_t*)(bias + c0);
      f4_t out;
#pragma unroll
      for (int j = 0; j < 4; ++j){
        float v = di * (s[j] + 2.0f * z4[j]) + b4[j];
        if (relu) v = fmaxf(v, 0.f);
        out[j] = v;
      }
      *(f4_t*)(Of + o) = out;
      if (SC){
        f4_t w4 = *(const f4_t*)(scw + c0);
#pragma unroll
        for (int j = 0; j < 4; ++j){ o_d += out[j] * w4[j]; o_q += w4[j] * w4[j]; }
      }
    } else if (EPI == 3){
      us4_t h4, l4v;
#pragma unroll
      for (int j = 0; j < 4; ++j){
        float v = (c0 + j == row) ? 0.f : s[j];
        unsigned short h = f2bf(v);
        h4[j] = h; l4v[j] = f2bf(v - bf2f(h));
        rsum += v;
      }
      *(us4_t*)(Oh + o) = h4;
      *(us4_t*)(Ol + o) = l4v;
    } else { // EPI == 4
      f4_t z4 = *(const f4_t*)(Zs + o);
      f4_t b4 = *(const f4_t*)(bias + c0);
      f4_t r4 = *(const f4_t*)(res + (size_t)prow * NC + c0);
      us4_t h4, l4v;
#pragma unroll
      for (int j = 0; j < 4; ++j){
        float v = di * (s[j] + 2.0f * z4[j]) + b4[j];
        if (relu) v = fmaxf(v, 0.f);
        float comb = r4[j] + v;
        unsigned short h = f2bf(comb);
        h4[j] = h; l4v[j] = f2bf(comb - bf2f(h));
      }
      size_t od = (size_t)prow * NC + c0;
      *(us4_t*)(Oh + od) = h4;
      *(us4_t*)(Ol + od) = l4v;
    }
  }
  if (EPI == 3){
    rsum = waveReduceSum(rsum);
    if (!lane) dout[row] = 1.0f / sqrtf(rsum + 2.0f);
  }
  if (SC){
    o_d = waveReduceSum(o_d);
    o_q = waveReduceSum(o_q);
    if (!lane) score[row] = tanhf(o_d / sqrtf(o_q));
  }
}

// ---------------- topk (stable descending rank) ----------------
__global__ void k_topk(const float* __restrict__ score, int n, int k,
                       int* __restrict__ perm, int* __restrict__ inv){
  int i = blockIdx.x; float si = score[i];
  int cnt = 0;
  for (int j = threadIdx.x; j < n; j += 256){
    float sj = score[j];
    if (sj > si || (sj == si && j < i)) cnt++;
  }
#pragma unroll
  for (int off = 32; off > 0; off >>= 1) cnt += __shfl_down(cnt, off);
  __shared__ int sh[4];
  int lane = threadIdx.x & 63, wid = threadIdx.x >> 6;
  if (lane == 0) sh[wid] = cnt;
  __syncthreads();
  if (threadIdx.x == 0){
    int rank = sh[0] + sh[1] + sh[2] + sh[3];
    if (rank < k){ perm[rank] = i; inv[i] = rank; }
    else inv[i] = -1;
  }
}

// ---------------- host orchestration ----------------
extern "C" void kernel_launch(void* const* d_in, const int* in_sizes, int n_in,
                              void* d_out, int out_size, void* d_ws, size_t ws_size,
                              hipStream_t stream){
  (void)in_sizes; (void)n_in; (void)out_size;
  const float* x_in = (const float*)d_in[0];
  const int*   ei   = (const int*)d_in[1];
  const float* dW0 = (const float*)d_in[2];
  const float* dW1 = (const float*)d_in[3];
  const float* dW2 = (const float*)d_in[4];
  const float* dW3 = (const float*)d_in[5];
  const float* db0 = (const float*)d_in[6];
  const float* db1 = (const float*)d_in[7];
  const float* db2 = (const float*)d_in[8];
  const float* db3 = (const float*)d_in[9];
  const float* pw0 = (const float*)d_in[10];
  const float* pw1 = (const float*)d_in[11];
  const float* pw2 = (const float*)d_in[12];
  const float* uW0 = (const float*)d_in[13];
  const float* uW1 = (const float*)d_in[14];
  const float* uW2 = (const float*)d_in[15];
  const float* ub0 = (const float*)d_in[16];
  const float* ub1 = (const float*)d_in[17];
  const float* ub2 = (const float*)d_in[18];

  char* p = (char*)d_ws;
  auto alloc = [&](size_t nbytes) -> void* {
    void* q = (void*)p; p += (nbytes + 255) & ~(size_t)255; return q;
  };
  unsigned* bits = (unsigned*)alloc((size_t)4096 * 128 * 4);
  int* ell = (int*)alloc((size_t)4096 * ECAP * 4);
  int* cnt = (int*)alloc(4096 * 4);
  int* inv1 = (int*)alloc(4096 * 4);
  int* inv2 = (int*)alloc(2048 * 4);
  int* inv3 = (int*)alloc(1024 * 4);
  unsigned short* Rb2 = (unsigned short*)alloc((size_t)4096 * 256 * 2);  // 2-bit packed
  float* Pp = (float*)alloc((size_t)16 * 1024 * 1024);   // split-K partials (16 MB)
  unsigned short* A1h = (unsigned short*)alloc((size_t)2048 * 2048 * 2);
  unsigned short* A2h = (unsigned short*)alloc((size_t)1024 * 1024 * 2);
  unsigned short* A2l = (unsigned short*)alloc((size_t)1024 * 1024 * 2);
  unsigned short* A3h = (unsigned short*)alloc((size_t)512 * 512 * 2);
  unsigned short* A3l = (unsigned short*)alloc((size_t)512 * 512 * 2);
  unsigned short* Lb2h = (unsigned short*)alloc((size_t)1024 * 2048 * 2);
  unsigned short* Rt2h = (unsigned short*)alloc((size_t)1024 * 2048 * 2);
  unsigned short* Lb3h = (unsigned short*)alloc((size_t)512 * 1024 * 2);
  unsigned short* Lb3l = (unsigned short*)alloc((size_t)512 * 1024 * 2);
  unsigned short* Rt3h = (unsigned short*)alloc((size_t)512 * 1024 * 2);
  unsigned short* Rt3l = (unsigned short*)alloc((size_t)512 * 1024 * 2);
  unsigned short* xinh = (unsigned short*)alloc((size_t)4096 * 512 * 2);
  unsigned short* xinl = (unsigned short*)alloc((size_t)4096 * 512 * 2);
  float* x0 = (float*)alloc((size_t)4096 * HID * 4);
  float* x1 = (float*)alloc((size_t)2048 * HID * 4);
  float* x2 = (float*)alloc((size_t)1024 * HID * 4);
  unsigned short* xu1h = (unsigned short*)alloc((size_t)4096 * HID * 2);
  unsigned short* xu1l = (unsigned short*)alloc((size_t)4096 * HID * 2);
  unsigned short* xu2h = (unsigned short*)alloc((size_t)2048 * HID * 2);
  unsigned short* xu2l = (unsigned short*)alloc((size_t)2048 * HID * 2);
  unsigned short* xu3h = (unsigned short*)alloc((size_t)1024 * HID * 2);
  unsigned short* xu3l = (unsigned short*)alloc((size_t)1024 * HID * 2);
  unsigned short* xph = (unsigned short*)alloc((size_t)2048 * HID * 2);
  unsigned short* xpl = (unsigned short*)alloc((size_t)2048 * HID * 2);
  unsigned short* W0th = (unsigned short*)alloc((size_t)256 * 512 * 2);
  unsigned short* W0tl = (unsigned short*)alloc((size_t)256 * 512 * 2);
  unsigned short* W5th = (unsigned short*)alloc((size_t)5 * 256 * 256 * 2);
  unsigned short* W5tl = (unsigned short*)alloc((size_t)5 * 256 * 256 * 2);
  unsigned short* W2th = (unsigned short*)alloc((size_t)64 * 256 * 2);
  unsigned short* W2tl = (unsigned short*)alloc((size_t)64 * 256 * 2);
  float* Zs  = (float*)alloc((size_t)4096 * HID * 4);
  unsigned short* ZsTh = (unsigned short*)alloc((size_t)256 * 2048 * 2);
  unsigned short* ZsTl = (unsigned short*)alloc((size_t)256 * 2048 * 2);
  float* dinv0 = (float*)alloc(4096 * 4);
  float* dinv1 = (float*)alloc(2048 * 4);
  float* dinv2 = (float*)alloc(1024 * 4);
  float* dinv3 = (float*)alloc(512 * 4);
  float* score = (float*)alloc(4096 * 4);
  int* perm1 = (int*)alloc(2048 * 4);
  int* perm2 = (int*)alloc(1024 * 4);
  int* perm3 = (int*)alloc(512 * 4);
  if ((size_t)(p - (char*)d_ws) > ws_size) return;

  // 1: prep (bits zero + x split + all weight tsplits)
  k_prep<<<2640, 256, 0, stream>>>(x_in, dW0, dW1, dW2, dW3, uW0, uW1, uW2, bits,
                                   xinh, xinl, W0th, W0tl, W5th, W5tl, W2th, W2tl);
  // 2-3: graph build
  k_build_bits<<<EE / 256, 256, 0, stream>>>(ei, bits);
  k_ell<<<4096, 128, 0, stream>>>(bits, ell, cnt, dinv0);

  // 4-5: conv0 (+ pool-1 score fused)
  { dim3 g(4, 64);
    k_mm<1,1,0,2><<<g, 256, 0, stream>>>(xinh, xinl, W0th, W0tl, 4096, HID, IN_DIM, IN_DIM,
                                         nullptr, Zs, nullptr, nullptr, dinv0); }
  k_spmm_ell<256,1,1><<<4096, 256, 0, stream>>>(ell, cnt, Zs, dinv0, db0, x0, pw0, score);

  // 6-8: pool 1 (4096 -> 2048)
  k_topk<<<4096, 256, 0, stream>>>(score, 4096, 2048, perm1, inv1);
  k_pool_build<<<10240, 256, 0, stream>>>(x0, score, perm1, inv1, ell, cnt,
                                          xph, xpl, Rb2, xu1h, xu1l);
  k_sq1<<<2048, 256, 0, stream>>>(ell, cnt, perm1, Rb2, A1h, dinv1);
  // 9-11: conv1 (g1 EPI4; g2 split-K z=4; red -> x1 + score2)
  { dim3 g(4, 32);
    k_mm<1,1,0,4><<<g, 256, 0, stream>>>(xph, xpl, W5th, W5tl, 2048, HID, HID, HID,
                                         nullptr, Zs, ZsTh, ZsTl, dinv1); }
  { dim3 g(4, 32, 4);
    k_mm<0,1,0,0><<<g, 256, 0, stream>>>(A1h, nullptr, ZsTh, ZsTl, 2048, HID, 2048, 512,
                                         Pp, nullptr, nullptr, nullptr, nullptr); }
  k_red<2,1,4><<<512, 256, 0, stream>>>(Pp, 2048, 256, dinv1, Zs, db1,
                                        x1, nullptr, nullptr, nullptr, 1, pw1, score, nullptr, nullptr);

  // 12-15: pool 2 (2048 -> 1024)
  k_topk<<<2048, 256, 0, stream>>>(score, 2048, 1024, perm2, inv2);
  k_pp<0,0><<<8192, 256, 0, stream>>>(x1, score, perm2, inv2, 2048, 1024,
                                      xph, xpl, xu2h, xu2l, A1h, nullptr,
                                      Lb2h, nullptr, Rt2h, nullptr);
  { dim3 g(16, 16, 4);
    k_mm<0,0,0,0><<<g, 256, 0, stream>>>(Lb2h, nullptr, Rt2h, nullptr, 1024, 1024, 2048, 512,
                                         Pp, nullptr, nullptr, nullptr, nullptr); }
  k_red<3,0,4><<<256, 256, 0, stream>>>(Pp, 1024, 1024, nullptr, nullptr, nullptr,
                                        nullptr, A2h, A2l, dinv2, 0, nullptr, nullptr, nullptr, nullptr);
  // 16-18: conv2
  { dim3 g(4, 16);
    k_mm<1,1,0,4><<<g, 256, 0, stream>>>(xph, xpl, W5th + 65536, W5tl + 65536, 1024, HID, HID, HID,
                                         nullptr, Zs, ZsTh, ZsTl, dinv2); }
  { dim3 g(4, 16, 4);
    k_mm<1,1,0,0><<<g, 256, 0, stream>>>(A2h, A2l, ZsTh, ZsTl, 1024, HID, 1024, 256,
                                         Pp, nullptr, nullptr, nullptr, nullptr); }
  k_red<2,1,4><<<256, 256, 0, stream>>>(Pp, 1024, 256, dinv2, Zs, db2,
                                        x2, nullptr, nullptr, nullptr, 1, pw2, score, nullptr, nullptr);

  // 19-22: pool 3 (1024 -> 512)
  k_topk<<<1024, 256, 0, stream>>>(score, 1024, 512, perm3, inv3);
  k_pp<1,1><<<3072, 256, 0, stream>>>(x2, score, perm3, inv3, 1024, 512,
                                      xph, xpl, xu3h, xu3l, A2h, A2l,
                                      Lb3h, Lb3l, Rt3h, Rt3l);
  { dim3 g(8, 8, 4);
    k_mm<1,1,1,0><<<g, 256, 0, stream>>>(Lb3h, Lb3l, Rt3h, Rt3l, 512, 512, 1024, 256,
                                         Pp, nullptr, nullptr, nullptr, nullptr); }
  k_red<3,0,4><<<128, 256, 0, stream>>>(Pp, 512, 512, nullptr, nullptr, nullptr,
                                        nullptr, A3h, A3l, dinv3, 0, nullptr, nullptr, nullptr, nullptr);
  // 23-25: conv3 -> scatter into xu3
  { dim3 g(4, 8);
    k_mm<1,1,0,4><<<g, 256, 0, stream>>>(xph, xpl, W5th + 2 * 65536, W5tl + 2 * 65536, 512, HID, HID, HID,
                                         nullptr, Zs, ZsTh, ZsTl, dinv3); }
  { dim3 g(4, 8, 4);
    k_mm<1,1,0,0><<<g, 256, 0, stream>>>(A3h, A3l, ZsTh, ZsTl, 512, HID, 512, 128,
                                         Pp, nullptr, nullptr, nullptr, nullptr); }
  k_red<4,0,4><<<128, 256, 0, stream>>>(Pp, 512, 256, dinv3, Zs, db3,
                                        nullptr, xu3h, xu3l, nullptr, 1, nullptr, nullptr, x2, perm3);

  // 26-28: up0 -> scatter into xu2
  { dim3 g(4, 16);
    k_mm<1,1,0,4><<<g, 256, 0, stream>>>(xu3h, xu3l, W5th + 3 * 65536, W5tl + 3 * 65536, 1024, HID, HID, HID,
                                         nullptr, Zs, ZsTh, ZsTl, dinv2); }
  { dim3 g(4, 16, 4);
    k_mm<1,1,0,0><<<g, 256, 0, stream>>>(A2h, A2l, ZsTh, ZsTl, 1024, HID, 1024, 256,
                                         Pp, nullptr, nullptr, nullptr, nullptr); }
  k_red<4,0,4><<<256, 256, 0, stream>>>(Pp, 1024, 256, dinv2, Zs, ub0,
                                        nullptr, xu2h, xu2l, nullptr, 1, nullptr, nullptr, x1, perm2);

  // 29-31: up1 -> scatter into xu1
  { dim3 g(4, 32);
    k_mm<1,1,0,4><<<g, 256, 0, stream>>>(xu2h, xu2l, W5th + 4 * 65536, W5tl + 4 * 65536, 2048, HID, HID, HID,
                                         nullptr, Zs, ZsTh, ZsTl, dinv1); }
  { dim3 g(4, 32, 4);
    k_mm<0,1,0,0><<<g, 256, 0, stream>>>(A1h, nullptr, ZsTh, ZsTl, 2048, HID, 2048, 512,
                                         Pp, nullptr, nullptr, nullptr, nullptr); }
  k_red<4,0,4><<<512, 256, 0, stream>>>(Pp, 2048, 256, dinv1, Zs, ub1,
                                        nullptr, xu1h, xu1l, nullptr, 1, nullptr, nullptr, x0, perm1);

  // 32-33: up2 (A0 sparse, Cout=64, no relu)
  { dim3 g(1, 64);
    k_mm<1,1,0,2><<<g, 256, 0, stream>>>(xu1h, xu1l, W2th, W2tl, 4096, OUT_DIM, HID, HID,
                                         nullptr, Zs, nullptr, nullptr, dinv0); }
  k_spmm_ell<64,0,0><<<4096, 256, 0, stream>>>(ell, cnt, Zs, dinv0, ub2, (float*)d_out, nullptr, nullptr);
}

// Round 12
// 222.268 us; speedup vs baseline: 1.0849x; 1.0117x over previous
//
#include <hip/hip_runtime.h>
#include <math.h>

#define NN 4096
#define EE 131072
#define IN_DIM 512
#define HID 256
#define OUT_DIM 64
#define ECAP 128

typedef __attribute__((ext_vector_type(8))) short bf8_t;
typedef __attribute__((ext_vector_type(4))) float f4_t;
typedef __attribute__((ext_vector_type(8))) unsigned short us8_t;
typedef __attribute__((ext_vector_type(4))) unsigned short us4_t;

#define GAS __attribute__((address_space(1)))
#define LAS __attribute__((address_space(3)))

// ---------------- bf16 helpers (RNE) ----------------
__device__ __forceinline__ unsigned short f2bf(float v){
  union { float f; unsigned u; } x; x.f = v;
  unsigned r = x.u + 0x7fffu + ((x.u >> 16) & 1u);
  return (unsigned short)(r >> 16);
}
__device__ __forceinline__ float bf2f(unsigned short h){
  union { float f; unsigned u; } x; x.u = ((unsigned)h) << 16;
  return x.f;
}

__device__ __forceinline__ float waveReduceSum(float v){
#pragma unroll
  for (int off = 32; off > 0; off >>= 1) v += __shfl_down(v, off);
  return v;
}

// ---------------- mega-prep: zero bits + split x_in + transpose-split all weights ----------------
__global__ __launch_bounds__(256) void k_prep(
    const float* __restrict__ x_in, const float* __restrict__ dW0,
    const float* __restrict__ dW1, const float* __restrict__ dW2,
    const float* __restrict__ dW3, const float* __restrict__ uW0,
    const float* __restrict__ uW1, const float* __restrict__ uW2,
    unsigned* __restrict__ bits,
    unsigned short* __restrict__ xinh, unsigned short* __restrict__ xinl,
    unsigned short* __restrict__ W0th, unsigned short* __restrict__ W0tl,
    unsigned short* __restrict__ W5th, unsigned short* __restrict__ W5tl,
    unsigned short* __restrict__ W2th, unsigned short* __restrict__ W2tl)
{
  int b = blockIdx.x;
  if (b < 128){                       // zero 2MB bit-adjacency
    int base = b * 4096 + threadIdx.x;
#pragma unroll
    for (int i = 0; i < 16; ++i) bits[base + i * 256] = 0;
    return;
  }
  b -= 128;
  if (b < 2048){                      // split x_in (4096x512 fp32 -> bf16 hi/lo)
    int i0 = b * 1024 + threadIdx.x;
#pragma unroll
    for (int i = 0; i < 4; ++i){
      int idx = i0 + i * 256;
      float v = x_in[idx];
      unsigned short h = f2bf(v);
      xinh[idx] = h; xinl[idx] = f2bf(v - bf2f(h));
    }
    return;
  }
  b -= 2048;
  const float* X; unsigned short *Th, *Tl; int R, C, tile;
  if (b < 128){ X = dW0; Th = W0th; Tl = W0tl; R = 512; C = 256; tile = b; }
  else if (b < 448){
    int t2 = b - 128; int z = t2 >> 6; int rem = t2 & 63;
    const float* ws[5] = {dW1, dW2, dW3, uW0, uW1};
    X = ws[z]; Th = W5th + (size_t)z * 65536; Tl = W5tl + (size_t)z * 65536;
    R = 256; C = 256; tile = rem;
  } else { X = uW2; Th = W2th; Tl = W2tl; R = 256; C = 64; tile = b - 448; }
  int tpr = C >> 5;
  int bx = (tile % tpr) * 32, by = (tile / tpr) * 32;
  __shared__ float t[32][33];
  int tx = threadIdx.x & 31, ty = threadIdx.x >> 5;
#pragma unroll
  for (int i = 0; i < 4; ++i)
    t[ty + i * 8][tx] = X[(size_t)(by + ty + i * 8) * C + bx + tx];
  __syncthreads();
#pragma unroll
  for (int i = 0; i < 4; ++i){
    float v = t[tx][ty + i * 8];
    unsigned short h = f2bf(v);
    size_t o = (size_t)(bx + ty + i * 8) * R + by + tx;
    Th[o] = h; Tl[o] = f2bf(v - bf2f(h));
  }
}

// ---------------- graph build: ELL from bitmask ----------------
__global__ __launch_bounds__(128) void k_ell(const unsigned* __restrict__ bits,
                                             int* __restrict__ ell, int* __restrict__ cnt,
                                             float* __restrict__ dinv){
  int r = blockIdx.x, t = threadIdx.x;
  unsigned w = bits[r * 128 + t];
  int c = __popc(w);
  __shared__ int sc[128];
  sc[t] = c; __syncthreads();
  for (int off = 1; off < 128; off <<= 1){
    int a = sc[t], b = (t >= off) ? sc[t - off] : 0;
    __syncthreads(); sc[t] = a + b; __syncthreads();
  }
  int total = sc[127];
  int pos = sc[t] - c;
  int base = r * ECAP;
  while (w){
    int b = __ffs(w) - 1; w &= w - 1;
    if (pos < ECAP) ell[base + pos] = t * 32 + b;
    pos++;
  }
  if (t == 0){
    cnt[r] = (total < ECAP) ? total : ECAP;
    dinv[r] = 1.0f / sqrtf((float)total + 2.0f);
  }
}

// ---------------- fused SpMM (ELL, values==1) + GCN epilogue (+ optional score) ----------------
// DS=1: Zs holds UNSCALED Z'; apply dinv[k] per gathered row and dinv[r] on diag term
// (bit-identical to gathering pre-scaled rows).
template<int NCOLS, int RELU, int SC, int DS>
__global__ __launch_bounds__(256) void k_spmm_ell(
    const int* __restrict__ ell, const int* __restrict__ cnt,
    const float* __restrict__ Zs, const float* __restrict__ dinv,
    const float* __restrict__ bias, float* __restrict__ out,
    const float* __restrict__ scw, float* __restrict__ score)
{
  int r = blockIdx.x;
  __shared__ int s_idx[ECAP];
  __shared__ float s_dv[ECAP];
  __shared__ int s_n;
  __shared__ float sh[4 * NCOLS];
  __shared__ float sd[4], sq[4];
  if (threadIdx.x == 0) s_n = cnt[r];
  __syncthreads();
  int n = s_n; if (n > ECAP) n = ECAP;
  for (int i = threadIdx.x; i < n; i += 256){
    int idx = ell[r * ECAP + i];
    s_idx[i] = idx;
    if (DS) s_dv[i] = dinv[idx];
  }
  __syncthreads();
  int wv = threadIdx.x >> 6, lane = threadIdx.x & 63;
  if (NCOLS == 256){
    f4_t acc = (f4_t){0.f, 0.f, 0.f, 0.f};
    for (int e = wv; e < n; e += 4){
      f4_t row = ((const f4_t*)(Zs + (size_t)s_idx[e] * 256))[lane];
      if (DS) row *= s_dv[e];
      acc += row;
    }
    ((f4_t*)(sh + wv * 256))[lane] = acc;
  } else {
    float acc = 0.f;
    for (int e = wv; e < n; e += 4){
      float v = Zs[(size_t)s_idx[e] * 64 + lane];
      if (DS) v *= s_dv[e];
      acc += v;
    }
    sh[wv * 64 + lane] = acc;
  }
  __syncthreads();
  int t = threadIdx.x;
  float o = 0.f;
  if (t < NCOLS){
    float y = sh[t] + sh[NCOLS + t] + sh[2 * NCOLS + t] + sh[3 * NCOLS + t];
    float di = dinv[r];
    float z = Zs[(size_t)r * NCOLS + t];
    if (DS) z = di * z;
    o = di * (y + 2.0f * z) + bias[t];
    if (RELU) o = fmaxf(o, 0.f);
    out[(size_t)r * NCOLS + t] = o;
  }
  if (SC){
    float w = scw[t];
    float d = waveReduceSum(o * w);
    float q = waveReduceSum(w * w);
    if (!lane){ sd[wv] = d; sq[wv] = q; }
    __syncthreads();
    if (!t) score[r] = tanhf((sd[0] + sd[1] + sd[2] + sd[3]) / sqrtf(sq[0] + sq[1] + sq[2] + sq[3]));
  }
}

// ---------------- pool1: pool_x2 + build_Rb (2-bit packed) + xu1 fill ----------------
__global__ __launch_bounds__(256) void k_pool_build(
    const float* __restrict__ x0, const float* __restrict__ score,
    const int* __restrict__ perm1, const int* __restrict__ inv1,
    const int* __restrict__ ell, const int* __restrict__ cnt,
    unsigned short* __restrict__ xph, unsigned short* __restrict__ xpl,
    unsigned short* __restrict__ Rb2,
    unsigned short* __restrict__ xu1h, unsigned short* __restrict__ xu1l)
{
  int b = blockIdx.x;
  if (b < 2048){                           // gated pooled features
    int pr = perm1[b]; float s = score[pr];
    int c = threadIdx.x;
    float v = x0[(size_t)pr * 256 + c] * s;
    unsigned short h = f2bf(v);
    xph[(size_t)b * 256 + c] = h;
    xpl[(size_t)b * 256 + c] = f2bf(v - bf2f(h));
    return;
  }
  if (b < 6144){                           // Rb2[k]: 2-bit packed (A0+I)[k][perm1[s]]
    int k = b - 2048;
    __shared__ unsigned char row[2048];
    for (int i = threadIdx.x; i < 512; i += 256) ((int*)row)[i] = 0;
    __syncthreads();
    int n = cnt[k];
    for (int e = threadIdx.x; e < n; e += 256){
      int s = inv1[ell[k * ECAP + e]];
      if (s >= 0) row[s] = 1;
    }
    __syncthreads();
    if (threadIdx.x == 0){
      int sk = inv1[k];
      if (sk >= 0) row[sk] += 1;
    }
    __syncthreads();
    unsigned w = 0;
#pragma unroll
    for (int j = 0; j < 8; ++j) w |= ((unsigned)row[(threadIdx.x << 3) + j]) << (2 * j);
    Rb2[k * 256 + threadIdx.x] = (unsigned short)w;
    return;
  }
  int r = b - 6144;                        // xu1 fill: non-selected rows = x0
  if (inv1[r] < 0){
    int c = threadIdx.x;
    float v = x0[(size_t)r * 256 + c];
    unsigned short h = f2bf(v);
    xu1h[(size_t)r * 256 + c] = h;
    xu1l[(size_t)r * 256 + c] = f2bf(v - bf2f(h));
  }
}

// ---------------- pool2/3 prep: pooled-x + xu fill + L row-gather(+I) + transpose-gather(+I) ----------------
template<int SRCL, int OUTL>
__global__ __launch_bounds__(256) void k_pp(
    const float* __restrict__ x, const float* __restrict__ score,
    const int* __restrict__ perm, const int* __restrict__ inv, int n, int k,
    unsigned short* __restrict__ xph, unsigned short* __restrict__ xpl,
    unsigned short* __restrict__ xuh, unsigned short* __restrict__ xul,
    const unsigned short* __restrict__ Ah, const unsigned short* __restrict__ Al,
    unsigned short* __restrict__ Lh, unsigned short* __restrict__ Ll,
    unsigned short* __restrict__ Rh, unsigned short* __restrict__ Rl)
{
  __shared__ float t[32][33];
  __shared__ int sinv[32];
  int b = blockIdx.x, c = threadIdx.x;
  if (b < k){
    int pr = perm[b]; float s = score[pr];
    float v = x[(size_t)pr * 256 + c] * s;
    unsigned short h = f2bf(v);
    xph[(size_t)b * 256 + c] = h;
    xpl[(size_t)b * 256 + c] = f2bf(v - bf2f(h));
    return;
  }
  b -= k;
  if (b < n){
    if (inv[b] < 0){
      float v = x[(size_t)b * 256 + c];
      unsigned short h = f2bf(v);
      xuh[(size_t)b * 256 + c] = h;
      xul[(size_t)b * 256 + c] = f2bf(v - bf2f(h));
    }
    return;
  }
  b -= n;
  if (b < k){
    int r = b, pr = perm[r];
    for (int cc = threadIdx.x; cc < n; cc += 256){
      float v = bf2f(Ah[(size_t)pr * n + cc]);
      if (SRCL) v += bf2f(Al[(size_t)pr * n + cc]);
      if (pr == cc) v += 1.f;
      unsigned short h = f2bf(v);
      Lh[(size_t)r * n + cc] = h;
      if (OUTL) Ll[(size_t)r * n + cc] = f2bf(v - bf2f(h));
    }
    return;
  }
  b -= k;
  int tpr = n >> 5;
  int kt = b / tpr, ct = b - kt * tpr;
  int tx = threadIdx.x & 31, ty = threadIdx.x >> 5;
  if (threadIdx.x < 32) sinv[threadIdx.x] = inv[ct * 32 + threadIdx.x];
#pragma unroll
  for (int i = 0; i < 4; ++i){
    int kl = ty + i * 8;
    size_t src = (size_t)(kt * 32 + kl) * n + ct * 32 + tx;
    float v = bf2f(Ah[src]);
    if (SRCL) v += bf2f(Al[src]);
    t[kl][tx] = v;
  }
  __syncthreads();
#pragma unroll
  for (int i = 0; i < 4; ++i){
    int cl = ty + i * 8;
    int s = sinv[cl];
    if (s >= 0){
      float v = t[tx][cl];
      if (kt * 32 + tx == ct * 32 + cl) v += 1.f;
      unsigned short h = f2bf(v);
      size_t o = (size_t)s * n + kt * 32 + tx;
      Rh[o] = h;
      if (OUTL) Rl[o] = f2bf(v - bf2f(h));
    }
  }
}

// ---------------- pool-1 squaring from ELL (2-bit packed Rb) ----------------
__global__ __launch_bounds__(256) void k_sq1(const int* __restrict__ ell, const int* __restrict__ cnt,
                                             const int* __restrict__ perm,
                                             const unsigned short* __restrict__ Rb2,
                                             unsigned short* __restrict__ A1h,
                                             float* __restrict__ dinv1){
  int r = blockIdx.x;
  int pr = perm[r];
  __shared__ int s_idx[ECAP];
  __shared__ int s_n;
  __shared__ float sred[4];
  if (threadIdx.x == 0) s_n = cnt[pr];
  for (int i = threadIdx.x; i < ECAP; i += 256) s_idx[i] = ell[pr * ECAP + i];
  __syncthreads();
  int n = s_n; if (n > ECAP) n = ECAP;
  int colb = threadIdx.x * 8;
  auto expand = [](unsigned x) -> uint2 {
    uint2 e;
    e.x = (x & 3) | (((x >> 2) & 3) << 8) | (((x >> 4) & 3) << 16) | (((x >> 6) & 3) << 24);
    e.y = ((x >> 8) & 3) | (((x >> 10) & 3) << 8) | (((x >> 12) & 3) << 16) | (((x >> 14) & 3) << 24);
    return e;
  };
  uint2 acc = expand(Rb2[pr * 256 + threadIdx.x]);
  for (int e = 0; e < n; ++e){
    uint2 v = expand(Rb2[s_idx[e] * 256 + threadIdx.x]);
    acc.x += v.x; acc.y += v.y;   // bytewise, no carries (values <=130)
  }
  float fs = 0.f;
  us8_t o;
#pragma unroll
  for (int j = 0; j < 8; ++j){
    unsigned byte = ((j < 4 ? acc.x : acc.y) >> (8 * (j & 3))) & 0xFFu;
    if (colb + j == r) byte = 0;
    float f = (float)byte;
    fs += f;
    o[j] = f2bf(f);
  }
  *(us8_t*)(A1h + (size_t)r * 2048 + colb) = o;
  fs = waveReduceSum(fs);
  int lane = threadIdx.x & 63, wd = threadIdx.x >> 6;
  if (!lane) sred[wd] = fs;
  __syncthreads();
  if (!threadIdx.x)
    dinv1[r] = 1.0f / sqrtf(sred[0] + sred[1] + sred[2] + sred[3] + 2.0f);
}

// ---------------- MFMA GEMM body (device function): global_load_lds dbuf + XCD swizzle ----------------
// EPI 0: write fp32 partial P[z][M][N] (split-K)
// EPI 2: Cf = dinv[row]*acc
// EPI 4: sv = dinv[row]*acc; Cf = sv; Ch/Cl[col*M+row] = split(sv) via LDS transpose
// EPI 5: Cf = acc (plain)
template<int HAS_AL, int HAS_BL, int HAS_LL, int EPI>
__device__ __forceinline__ void mm_body(char* ldsc, int id, int nbx, int nby, int tot,
    const unsigned short* __restrict__ Ah, const unsigned short* __restrict__ Al,
    const unsigned short* __restrict__ Bh, const unsigned short* __restrict__ Bl,
    int M, int N, int K, int KS, float* __restrict__ P,
    float* __restrict__ Cf, unsigned short* __restrict__ Ch, unsigned short* __restrict__ Cl,
    const float* __restrict__ dinv)
{
  constexpr int NARR = 2 + HAS_AL + HAS_BL;
  constexpr int BUF = NARR * 8192;

  const int tid = threadIdx.x, lane = tid & 63, wid = tid >> 6;
  const int wm = wid >> 1, wn = wid & 1;
  if ((tot & 7) == 0) id = (id & 7) * (tot >> 3) + (id >> 3);
  const int sx = id % nbx; int remq = id / nbx;
  const int sy = remq % nby;
  const int bm = sy << 6, bn = sx << 6;
  const int z = remq / nby;
  const int l15 = lane & 15, l4 = lane >> 4;

  f4_t acc[2][2];
#pragma unroll
  for (int i = 0; i < 2; ++i)
#pragma unroll
    for (int j = 0; j < 2; ++j) acc[i][j] = (f4_t){0.f, 0.f, 0.f, 0.f};

  const size_t rb = (size_t)K * 2;
  const size_t kz = (size_t)z * KS * 2;
  const char* pAh = (const char*)Ah + (size_t)bm * rb;
  const char* pAl = HAS_AL ? (const char*)Al + (size_t)bm * rb : nullptr;
  const char* pBh = (const char*)Bh + (size_t)bn * rb;
  const char* pBl = HAS_BL ? (const char*)Bl + (size_t)bn * rb : nullptr;

  auto stage = [&](int t, int b2){
    char* ldsb = ldsc + b2 * BUF;
    const size_t kb = kz + (size_t)t * 128;
#pragma unroll
    for (int it = 0; it < 2; ++it){
      const int idx = tid + (it << 8);
      const int row = idx >> 3;
      const int kc = ((idx & 7) << 4) ^ ((row & 7) << 4);  // pre-swizzled source col
      const size_t go = (size_t)row * rb + kb + kc;
      const int lo = idx * 16;
      __builtin_amdgcn_global_load_lds((const GAS void*)(pAh + go), (LAS void*)(ldsb + lo), 16, 0, 0);
      __builtin_amdgcn_global_load_lds((const GAS void*)(pBh + go), (LAS void*)(ldsb + 8192 + lo), 16, 0, 0);
      if (HAS_AL)
        __builtin_amdgcn_global_load_lds((const GAS void*)(pAl + go), (LAS void*)(ldsb + 16384 + lo), 16, 0, 0);
      if (HAS_BL)
        __builtin_amdgcn_global_load_lds((const GAS void*)(pBl + go), (LAS void*)(ldsb + (2 + HAS_AL) * 8192 + lo), 16, 0, 0);
    }
  };

  const int T = KS >> 6;
  stage(0, 0);
  int b = 0;
  for (int t = 0; t < T; ++t){
    if (t + 1 < T){
      stage(t + 1, b ^ 1);
      if constexpr (NARR == 2) asm volatile("s_waitcnt vmcnt(4)" ::: "memory");
      else if constexpr (NARR == 3) asm volatile("s_waitcnt vmcnt(6)" ::: "memory");
      else asm volatile("s_waitcnt vmcnt(8)" ::: "memory");
    } else {
      asm volatile("s_waitcnt vmcnt(0)" ::: "memory");
    }
    __syncthreads();
    const char* ldsb = ldsc + b * BUF;
#pragma unroll
    for (int ks = 0; ks < 2; ++ks){
      bf8_t aH[2], aL[2], bH[2], bL[2];
#pragma unroll
      for (int f = 0; f < 2; ++f){
        int ar = wm * 32 + f * 16 + l15;
        int aoff = ar * 128 + (((ks * 64) + (l4 << 4)) ^ ((ar & 7) << 4));
        aH[f] = *(const bf8_t*)(ldsb + aoff);
        if (HAS_AL) aL[f] = *(const bf8_t*)(ldsb + 16384 + aoff);
        int br = wn * 32 + f * 16 + l15;
        int boff = br * 128 + (((ks * 64) + (l4 << 4)) ^ ((br & 7) << 4));
        bH[f] = *(const bf8_t*)(ldsb + 8192 + boff);
        if (HAS_BL) bL[f] = *(const bf8_t*)(ldsb + (2 + HAS_AL) * 8192 + boff);
      }
#pragma unroll
      for (int i = 0; i < 2; ++i)
#pragma unroll
        for (int j = 0; j < 2; ++j){
          acc[i][j] = __builtin_amdgcn_mfma_f32_16x16x32_bf16(aH[i], bH[j], acc[i][j], 0, 0, 0);
          if (HAS_BL) acc[i][j] = __builtin_amdgcn_mfma_f32_16x16x32_bf16(aH[i], bL[j], acc[i][j], 0, 0, 0);
          if (HAS_AL) acc[i][j] = __builtin_amdgcn_mfma_f32_16x16x32_bf16(aL[i], bH[j], acc[i][j], 0, 0, 0);
          if (HAS_LL) acc[i][j] = __builtin_amdgcn_mfma_f32_16x16x32_bf16(aL[i], bL[j], acc[i][j], 0, 0, 0);
        }
    }
    __syncthreads();
    b ^= 1;
  }

  if (EPI == 4){
    float* LT = (float*)ldsc;   // [64][68] fp32 = 17.4 KB
#pragma unroll
    for (int i = 0; i < 2; ++i)
#pragma unroll
      for (int j = 0; j < 2; ++j)
#pragma unroll
        for (int r = 0; r < 4; ++r){
          int lr = wm * 32 + i * 16 + l4 * 4 + r;
          int lc = wn * 32 + j * 16 + l15;
          float sv = dinv[bm + lr] * acc[i][j][r];
          Cf[(size_t)(bm + lr) * N + bn + lc] = sv;
          LT[lr * 68 + lc] = sv;
        }
    __syncthreads();
    int col = tid >> 2;
    int seg = (tid & 3) << 4;
    us8_t h0, h1, l0, l1;
#pragma unroll
    for (int mm = 0; mm < 8; ++mm){
      float v = LT[(seg + mm) * 68 + col];
      unsigned short h = f2bf(v);
      h0[mm] = h; l0[mm] = f2bf(v - bf2f(h));
    }
#pragma unroll
    for (int mm = 0; mm < 8; ++mm){
      float v = LT[(seg + 8 + mm) * 68 + col];
      unsigned short h = f2bf(v);
      h1[mm] = h; l1[mm] = f2bf(v - bf2f(h));
    }
    size_t ob = (size_t)(bn + col) * M + bm + seg;
    *(us8_t*)(Ch + ob) = h0;
    *(us8_t*)(Ch + ob + 8) = h1;
    *(us8_t*)(Cl + ob) = l0;
    *(us8_t*)(Cl + ob + 8) = l1;
    return;
  }

  float* Pz = (EPI == 0) ? P + (size_t)z * M * N : nullptr;
#pragma unroll
  for (int i = 0; i < 2; ++i)
#pragma unroll
    for (int j = 0; j < 2; ++j)
#pragma unroll
      for (int r = 0; r < 4; ++r){
        int grow = bm + wm * 32 + i * 16 + l4 * 4 + r;
        int gcol = bn + wn * 32 + j * 16 + l15;
        float v = acc[i][j][r];
        size_t o = (size_t)grow * N + gcol;
        if (EPI == 0){
          Pz[o] = v;
        } else if (EPI == 2){
          Cf[o] = dinv[grow] * v;
        } else { // EPI == 5
          Cf[o] = v;
        }
      }
}

// thin wrapper kernel
template<int HAS_AL, int HAS_BL, int HAS_LL, int EPI>
__global__ __launch_bounds__(256) void k_mm(
    const unsigned short* __restrict__ Ah, const unsigned short* __restrict__ Al,
    const unsigned short* __restrict__ Bh, const unsigned short* __restrict__ Bl,
    int M, int N, int K, int KS, float* __restrict__ P,
    float* __restrict__ Cf, unsigned short* __restrict__ Ch, unsigned short* __restrict__ Cl,
    const float* __restrict__ dinv)
{
  constexpr int NARR = 2 + HAS_AL + HAS_BL;
  __shared__ int4 ldsq[NARR * 512 * 2];
  const int nbx = gridDim.x, nby = gridDim.y;
  const int tot = nbx * nby * gridDim.z;
  int id = blockIdx.x + nbx * (blockIdx.y + nby * blockIdx.z);
  mm_body<HAS_AL, HAS_BL, HAS_LL, EPI>((char*)ldsq, id, nbx, nby, tot,
      Ah, Al, Bh, Bl, M, N, K, KS, P, Cf, Ch, Cl, dinv);
}

// ---------------- fused: build_bits (blocks [0,512)) || conv0-g1 unscaled (blocks [512,768)) ----------------
__global__ __launch_bounds__(256) void k_fuse0(
    const int* __restrict__ ei, unsigned* __restrict__ bits,
    const unsigned short* __restrict__ Ah, const unsigned short* __restrict__ Al,
    const unsigned short* __restrict__ Bh, const unsigned short* __restrict__ Bl,
    float* __restrict__ Cf)
{
  __shared__ int4 ldsq[4 * 512 * 2];   // 64KB, used by mm path only
  if (blockIdx.x < 512){
    int e = blockIdx.x * 256 + threadIdx.x;
    int r = ei[e], c = ei[EE + e];
    atomicOr(&bits[r * 128 + (c >> 5)], 1u << (c & 31));
    return;
  }
  int id = blockIdx.x - 512;  // 256 mm blocks: nbx=4, nby=64, tot=256
  mm_body<1,1,0,5>((char*)ldsq, id, 4, 64, 256,
      Ah, Al, Bh, Bl, 4096, HID, IN_DIM, IN_DIM,
      nullptr, Cf, nullptr, nullptr, nullptr);
}

// ---------------- split-K reduce, wave-per-row, float4 (4 rows per block) ----------------
template<int EPI, int SC, int Z>
__global__ __launch_bounds__(256) void k_red(
    const float* __restrict__ P, int M, int NC,
    const float* __restrict__ dinv, const float* __restrict__ Zs,
    const float* __restrict__ bias,
    float* __restrict__ Of, unsigned short* __restrict__ Oh, unsigned short* __restrict__ Ol,
    float* __restrict__ dout, int relu,
    const float* __restrict__ scw, float* __restrict__ score,
    const float* __restrict__ res, const int* __restrict__ permsel)
{
  int w = threadIdx.x >> 6, lane = threadIdx.x & 63;
  int row = blockIdx.x * 4 + w;
  int prow = (EPI == 4) ? permsel[row] : 0;
  float di = (EPI != 3) ? dinv[row] : 0.f;
  float rsum = 0.f, o_d = 0.f, o_q = 0.f;
  for (int c0 = lane * 4; c0 < NC; c0 += 256){
    size_t o = (size_t)row * NC + c0;
    f4_t s = *(const f4_t*)(P + o);
#pragma unroll
    for (int zz = 1; zz < Z; ++zz) s += *(const f4_t*)(P + (size_t)zz * M * NC + o);
    if (EPI == 2){
      f4_t z4 = *(const f4_t*)(Zs + o);
      f4_t b4 = *(const f4_t*)(bias + c0);
      f4_t out;
#pragma unroll
      for (int j = 0; j < 4; ++j){
        float v = di * (s[j] + 2.0f * z4[j]) + b4[j];
        if (relu) v = fmaxf(v, 0.f);
        out[j] = v;
      }
      *(f4_t*)(Of + o) = out;
      if (SC){
        f4_t w4 = *(const f4_t*)(scw + c0);
#pragma unroll
        for (int j = 0; j < 4; ++j){ o_d += out[j] * w4[j]; o_q += w4[j] * w4[j]; }
      }
    } else if (EPI == 3){
      us4_t h4, l4v;
#pragma unroll
      for (int j = 0; j < 4; ++j){
        float v = (c0 + j == row) ? 0.f : s[j];
        unsigned short h = f2bf(v);
        h4[j] = h; l4v[j] = f2bf(v - bf2f(h));
        rsum += v;
      }
      *(us4_t*)(Oh + o) = h4;
      *(us4_t*)(Ol + o) = l4v;
    } else { // EPI == 4
      f4_t z4 = *(const f4_t*)(Zs + o);
      f4_t b4 = *(const f4_t*)(bias + c0);
      f4_t r4 = *(const f4_t*)(res + (size_t)prow * NC + c0);
      us4_t h4, l4v;
#pragma unroll
      for (int j = 0; j < 4; ++j){
        float v = di * (s[j] + 2.0f * z4[j]) + b4[j];
        if (relu) v = fmaxf(v, 0.f);
        float comb = r4[j] + v;
        unsigned short h = f2bf(comb);
        h4[j] = h; l4v[j] = f2bf(comb - bf2f(h));
      }
      size_t od = (size_t)prow * NC + c0;
      *(us4_t*)(Oh + od) = h4;
      *(us4_t*)(Ol + od) = l4v;
    }
  }
  if (EPI == 3){
    rsum = waveReduceSum(rsum);
    if (!lane) dout[row] = 1.0f / sqrtf(rsum + 2.0f);
  }
  if (SC){
    o_d = waveReduceSum(o_d);
    o_q = waveReduceSum(o_q);
    if (!lane) score[row] = tanhf(o_d / sqrtf(o_q));
  }
}

// ---------------- topk (stable descending rank) ----------------
__global__ void k_topk(const float* __restrict__ score, int n, int k,
                       int* __restrict__ perm, int* __restrict__ inv){
  int i = blockIdx.x; float si = score[i];
  int cnt = 0;
  for (int j = threadIdx.x; j < n; j += 256){
    float sj = score[j];
    if (sj > si || (sj == si && j < i)) cnt++;
  }
#pragma unroll
  for (int off = 32; off > 0; off >>= 1) cnt += __shfl_down(cnt, off);
  __shared__ int sh[4];
  int lane = threadIdx.x & 63, wid = threadIdx.x >> 6;
  if (lane == 0) sh[wid] = cnt;
  __syncthreads();
  if (threadIdx.x == 0){
    int rank = sh[0] + sh[1] + sh[2] + sh[3];
    if (rank < k){ perm[rank] = i; inv[i] = rank; }
    else inv[i] = -1;
  }
}

// ---------------- host orchestration ----------------
extern "C" void kernel_launch(void* const* d_in, const int* in_sizes, int n_in,
                              void* d_out, int out_size, void* d_ws, size_t ws_size,
                              hipStream_t stream){
  (void)in_sizes; (void)n_in; (void)out_size;
  const float* x_in = (const float*)d_in[0];
  const int*   ei   = (const int*)d_in[1];
  const float* dW0 = (const float*)d_in[2];
  const float* dW1 = (const float*)d_in[3];
  const float* dW2 = (const float*)d_in[4];
  const float* dW3 = (const float*)d_in[5];
  const float* db0 = (const float*)d_in[6];
  const float* db1 = (const float*)d_in[7];
  const float* db2 = (const float*)d_in[8];
  const float* db3 = (const float*)d_in[9];
  const float* pw0 = (const float*)d_in[10];
  const float* pw1 = (const float*)d_in[11];
  const float* pw2 = (const float*)d_in[12];
  const float* uW0 = (const float*)d_in[13];
  const float* uW1 = (const float*)d_in[14];
  const float* uW2 = (const float*)d_in[15];
  const float* ub0 = (const float*)d_in[16];
  const float* ub1 = (const float*)d_in[17];
  const float* ub2 = (const float*)d_in[18];

  char* p = (char*)d_ws;
  auto alloc = [&](size_t nbytes) -> void* {
    void* q = (void*)p; p += (nbytes + 255) & ~(size_t)255; return q;
  };
  unsigned* bits = (unsigned*)alloc((size_t)4096 * 128 * 4);
  int* ell = (int*)alloc((size_t)4096 * ECAP * 4);
  int* cnt = (int*)alloc(4096 * 4);
  int* inv1 = (int*)alloc(4096 * 4);
  int* inv2 = (int*)alloc(2048 * 4);
  int* inv3 = (int*)alloc(1024 * 4);
  unsigned short* Rb2 = (unsigned short*)alloc((size_t)4096 * 256 * 2);  // 2-bit packed
  float* Pp = (float*)alloc((size_t)16 * 1024 * 1024);   // split-K partials
  unsigned short* A1h = (unsigned short*)alloc((size_t)2048 * 2048 * 2);
  unsigned short* A2h = (unsigned short*)alloc((size_t)1024 * 1024 * 2);
  unsigned short* A2l = (unsigned short*)alloc((size_t)1024 * 1024 * 2);
  unsigned short* A3h = (unsigned short*)alloc((size_t)512 * 512 * 2);
  unsigned short* A3l = (unsigned short*)alloc((size_t)512 * 512 * 2);
  unsigned short* Lb2h = (unsigned short*)alloc((size_t)1024 * 2048 * 2);
  unsigned short* Rt2h = (unsigned short*)alloc((size_t)1024 * 2048 * 2);
  unsigned short* Lb3h = (unsigned short*)alloc((size_t)512 * 1024 * 2);
  unsigned short* Lb3l = (unsigned short*)alloc((size_t)512 * 1024 * 2);
  unsigned short* Rt3h = (unsigned short*)alloc((size_t)512 * 1024 * 2);
  unsigned short* Rt3l = (unsigned short*)alloc((size_t)512 * 1024 * 2);
  unsigned short* xinh = (unsigned short*)alloc((size_t)4096 * 512 * 2);
  unsigned short* xinl = (unsigned short*)alloc((size_t)4096 * 512 * 2);
  float* x0 = (float*)alloc((size_t)4096 * HID * 4);
  float* x1 = (float*)alloc((size_t)2048 * HID * 4);
  float* x2 = (float*)alloc((size_t)1024 * HID * 4);
  unsigned short* xu1h = (unsigned short*)alloc((size_t)4096 * HID * 2);
  unsigned short* xu1l = (unsigned short*)alloc((size_t)4096 * HID * 2);
  unsigned short* xu2h = (unsigned short*)alloc((size_t)2048 * HID * 2);
  unsigned short* xu2l = (unsigned short*)alloc((size_t)2048 * HID * 2);
  unsigned short* xu3h = (unsigned short*)alloc((size_t)1024 * HID * 2);
  unsigned short* xu3l = (unsigned short*)alloc((size_t)1024 * HID * 2);
  unsigned short* xph = (unsigned short*)alloc((size_t)2048 * HID * 2);
  unsigned short* xpl = (unsigned short*)alloc((size_t)2048 * HID * 2);
  unsigned short* W0th = (unsigned short*)alloc((size_t)256 * 512 * 2);
  unsigned short* W0tl = (unsigned short*)alloc((size_t)256 * 512 * 2);
  unsigned short* W5th = (unsigned short*)alloc((size_t)5 * 256 * 256 * 2);
  unsigned short* W5tl = (unsigned short*)alloc((size_t)5 * 256 * 256 * 2);
  unsigned short* W2th = (unsigned short*)alloc((size_t)64 * 256 * 2);
  unsigned short* W2tl = (unsigned short*)alloc((size_t)64 * 256 * 2);
  float* Zs  = (float*)alloc((size_t)4096 * HID * 4);
  unsigned short* ZsTh = (unsigned short*)alloc((size_t)256 * 2048 * 2);
  unsigned short* ZsTl = (unsigned short*)alloc((size_t)256 * 2048 * 2);
  float* dinv0 = (float*)alloc(4096 * 4);
  float* dinv1 = (float*)alloc(2048 * 4);
  float* dinv2 = (float*)alloc(1024 * 4);
  float* dinv3 = (float*)alloc(512 * 4);
  float* score = (float*)alloc(4096 * 4);
  int* perm1 = (int*)alloc(2048 * 4);
  int* perm2 = (int*)alloc(1024 * 4);
  int* perm3 = (int*)alloc(512 * 4);
  if ((size_t)(p - (char*)d_ws) > ws_size) return;

  // 1: prep (bits zero + x split + all weight tsplits)
  k_prep<<<2640, 256, 0, stream>>>(x_in, dW0, dW1, dW2, dW3, uW0, uW1, uW2, bits,
                                   xinh, xinl, W0th, W0tl, W5th, W5tl, W2th, W2tl);
  // 2: build_bits || conv0-g1 (unscaled Z')
  k_fuse0<<<768, 256, 0, stream>>>(ei, bits, xinh, xinl, W0th, W0tl, Zs);
  // 3: ELL + dinv0
  k_ell<<<4096, 128, 0, stream>>>(bits, ell, cnt, dinv0);
  // 4: conv0 spmm (scaled gather; + pool-1 score fused)
  k_spmm_ell<256,1,1,1><<<4096, 256, 0, stream>>>(ell, cnt, Zs, dinv0, db0, x0, pw0, score);

  // 5-7: pool 1 (4096 -> 2048)
  k_topk<<<4096, 256, 0, stream>>>(score, 4096, 2048, perm1, inv1);
  k_pool_build<<<10240, 256, 0, stream>>>(x0, score, perm1, inv1, ell, cnt,
                                          xph, xpl, Rb2, xu1h, xu1l);
  k_sq1<<<2048, 256, 0, stream>>>(ell, cnt, perm1, Rb2, A1h, dinv1);
  // 8-10: conv1 (g1 EPI4; g2 split-K z=4; red -> x1 + score2)
  { dim3 g(4, 32);
    k_mm<1,1,0,4><<<g, 256, 0, stream>>>(xph, xpl, W5th, W5tl, 2048, HID, HID, HID,
                                         nullptr, Zs, ZsTh, ZsTl, dinv1); }
  { dim3 g(4, 32, 4);
    k_mm<0,1,0,0><<<g, 256, 0, stream>>>(A1h, nullptr, ZsTh, ZsTl, 2048, HID, 2048, 512,
                                         Pp, nullptr, nullptr, nullptr, nullptr); }
  k_red<2,1,4><<<512, 256, 0, stream>>>(Pp, 2048, 256, dinv1, Zs, db1,
                                        x1, nullptr, nullptr, nullptr, 1, pw1, score, nullptr, nullptr);

  // 11-14: pool 2 (2048 -> 1024)
  k_topk<<<2048, 256, 0, stream>>>(score, 2048, 1024, perm2, inv2);
  k_pp<0,0><<<8192, 256, 0, stream>>>(x1, score, perm2, inv2, 2048, 1024,
                                      xph, xpl, xu2h, xu2l, A1h, nullptr,
                                      Lb2h, nullptr, Rt2h, nullptr);
  { dim3 g(16, 16, 4);
    k_mm<0,0,0,0><<<g, 256, 0, stream>>>(Lb2h, nullptr, Rt2h, nullptr, 1024, 1024, 2048, 512,
                                         Pp, nullptr, nullptr, nullptr, nullptr); }
  k_red<3,0,4><<<256, 256, 0, stream>>>(Pp, 1024, 1024, nullptr, nullptr, nullptr,
                                        nullptr, A2h, A2l, dinv2, 0, nullptr, nullptr, nullptr, nullptr);
  // 15-17: conv2
  { dim3 g(4, 16);
    k_mm<1,1,0,4><<<g, 256, 0, stream>>>(xph, xpl, W5th + 65536, W5tl + 65536, 1024, HID, HID, HID,
                                         nullptr, Zs, ZsTh, ZsTl, dinv2); }
  { dim3 g(4, 16, 4);
    k_mm<1,1,0,0><<<g, 256, 0, stream>>>(A2h, A2l, ZsTh, ZsTl, 1024, HID, 1024, 256,
                                         Pp, nullptr, nullptr, nullptr, nullptr); }
  k_red<2,1,4><<<256, 256, 0, stream>>>(Pp, 1024, 256, dinv2, Zs, db2,
                                        x2, nullptr, nullptr, nullptr, 1, pw2, score, nullptr, nullptr);

  // 18-21: pool 3 (1024 -> 512)
  k_topk<<<1024, 256, 0, stream>>>(score, 1024, 512, perm3, inv3);
  k_pp<1,1><<<3072, 256, 0, stream>>>(x2, score, perm3, inv3, 1024, 512,
                                      xph, xpl, xu3h, xu3l, A2h, A2l,
                                      Lb3h, Lb3l, Rt3h, Rt3l);
  { dim3 g(8, 8, 4);
    k_mm<1,1,1,0><<<g, 256, 0, stream>>>(Lb3h, Lb3l, Rt3h, Rt3l, 512, 512, 1024, 256,
                                         Pp, nullptr, nullptr, nullptr, nullptr); }
  k_red<3,0,4><<<128, 256, 0, stream>>>(Pp, 512, 512, nullptr, nullptr, nullptr,
                                        nullptr, A3h, A3l, dinv3, 0, nullptr, nullptr, nullptr, nullptr);
  // 22-24: conv3 -> scatter into xu3
  { dim3 g(4, 8);
    k_mm<1,1,0,4><<<g, 256, 0, stream>>>(xph, xpl, W5th + 2 * 65536, W5tl + 2 * 65536, 512, HID, HID, HID,
                                         nullptr, Zs, ZsTh, ZsTl, dinv3); }
  { dim3 g(4, 8, 4);
    k_mm<1,1,0,0><<<g, 256, 0, stream>>>(A3h, A3l, ZsTh, ZsTl, 512, HID, 512, 128,
                                         Pp, nullptr, nullptr, nullptr, nullptr); }
  k_red<4,0,4><<<128, 256, 0, stream>>>(Pp, 512, 256, dinv3, Zs, db3,
                                        nullptr, xu3h, xu3l, nullptr, 1, nullptr, nullptr, x2, perm3);

  // 25-27: up0 -> scatter into xu2
  { dim3 g(4, 16);
    k_mm<1,1,0,4><<<g, 256, 0, stream>>>(xu3h, xu3l, W5th + 3 * 65536, W5tl + 3 * 65536, 1024, HID, HID, HID,
                                         nullptr, Zs, ZsTh, ZsTl, dinv2); }
  { dim3 g(4, 16, 4);
    k_mm<1,1,0,0><<<g, 256, 0, stream>>>(A2h, A2l, ZsTh, ZsTl, 1024, HID, 1024, 256,
                                         Pp, nullptr, nullptr, nullptr, nullptr); }
  k_red<4,0,4><<<256, 256, 0, stream>>>(Pp, 1024, 256, dinv2, Zs, ub0,
                                        nullptr, xu2h, xu2l, nullptr, 1, nullptr, nullptr, x1, perm2);

  // 28-30: up1 -> scatter into xu1
  { dim3 g(4, 32);
    k_mm<1,1,0,4><<<g, 256, 0, stream>>>(xu2h, xu2l, W5th + 4 * 65536, W5tl + 4 * 65536, 2048, HID, HID, HID,
                                         nullptr, Zs, ZsTh, ZsTl, dinv1); }
  { dim3 g(4, 32, 4);
    k_mm<0,1,0,0><<<g, 256, 0, stream>>>(A1h, nullptr, ZsTh, ZsTl, 2048, HID, 2048, 512,
                                         Pp, nullptr, nullptr, nullptr, nullptr); }
  k_red<4,0,4><<<512, 256, 0, stream>>>(Pp, 2048, 256, dinv1, Zs, ub1,
                                        nullptr, xu1h, xu1l, nullptr, 1, nullptr, nullptr, x0, perm1);

  // 31-32: up2 (A0 sparse, Cout=64, no relu)
  { dim3 g(1, 64);
    k_mm<1,1,0,2><<<g, 256, 0, stream>>>(xu1h, xu1l, W2th, W2tl, 4096, OUT_DIM, HID, HID,
                                         nullptr, Zs, nullptr, nullptr, dinv0); }
  k_spmm_ell<64,0,0,0><<<4096, 256, 0, stream>>>(ell, cnt, Zs, dinv0, ub2, (float*)d_out, nullptr, nullptr);
}